// Round 2
// baseline (519.153 us; speedup 1.0000x reference)
//
#include <hip/hip_runtime.h>
#include <hip/hip_bf16.h>

// Problem constants: B=2, S=2048, DIM=2048, H=16, KVH=8, D=128
// qkv packed columns: [0,2048)=Q (h*128+d), [2048,3072)=K, [3072,4096)=V

typedef __attribute__((ext_vector_type(8))) short s16x8;   // 8 bf16 in 4 VGPRs
typedef __attribute__((ext_vector_type(4))) float f32x4;

static __device__ __forceinline__ unsigned short f2bf(float f) {
    union { float f; unsigned u; } v; v.f = f;
    unsigned r = v.u + 0x7FFF + ((v.u >> 16) & 1);   // RNE
    return (unsigned short)(r >> 16);
}
static __device__ __forceinline__ float bf2f(unsigned short h) {
    union { unsigned u; float f; } v; v.u = ((unsigned)h) << 16;
    return v.f;
}

// ---------------- f32 -> bf16 elementwise convert (x) ----------------
__global__ __launch_bounds__(256) void k_convert_x(const float* __restrict__ x,
                                                   unsigned short* __restrict__ xb, int n) {
    int i = (blockIdx.x * 256 + threadIdx.x) * 8;
    if (i >= n) return;
    float4 a = *(const float4*)(x + i);
    float4 b = *(const float4*)(x + i + 4);
    s16x8 o;
    o[0] = (short)f2bf(a.x); o[1] = (short)f2bf(a.y); o[2] = (short)f2bf(a.z); o[3] = (short)f2bf(a.w);
    o[4] = (short)f2bf(b.x); o[5] = (short)f2bf(b.y); o[6] = (short)f2bf(b.z); o[7] = (short)f2bf(b.w);
    *(s16x8*)(xb + i) = o;
}

// ---------------- weight transpose f32 (K x N) -> bf16 (N x K) ----------------
__global__ __launch_bounds__(256) void k_transpose_w(const float* __restrict__ src,
                                                     unsigned short* __restrict__ dst,
                                                     int K, int N, int nbase, int dstld) {
    __shared__ float t[32][33];
    int k0 = blockIdx.x * 32, n0 = blockIdx.y * 32;
    int tx = threadIdx.x & 31, ty0 = threadIdx.x >> 5;
    for (int p = 0; p < 4; p++) {
        int ty = ty0 + p * 8;
        t[ty][tx] = src[(size_t)(k0 + ty) * N + n0 + tx];
    }
    __syncthreads();
    for (int p = 0; p < 4; p++) {
        int ty = ty0 + p * 8;
        dst[(size_t)(nbase + n0 + ty) * dstld + k0 + tx] = f2bf(t[tx][ty]);
    }
}

// ---------------- bf16 transpose: V (2048 x 128) -> Vt (128 x 2048), per (b,kvh) ----------------
__global__ __launch_bounds__(256) void k_transpose_v(const unsigned short* __restrict__ V,
                                                     unsigned short* __restrict__ Vt) {
    __shared__ unsigned short t[32][33];
    int s0 = blockIdx.x * 32, d0 = blockIdx.y * 32;
    size_t base = (size_t)blockIdx.z * 2048 * 128;
    int tx = threadIdx.x & 31, ty0 = threadIdx.x >> 5;
    for (int p = 0; p < 4; p++) {
        int ty = ty0 + p * 8;
        t[ty][tx] = V[base + (size_t)(s0 + ty) * 128 + d0 + tx];
    }
    __syncthreads();
    for (int p = 0; p < 4; p++) {
        int ty = ty0 + p * 8;
        Vt[base + (size_t)(d0 + ty) * 2048 + s0 + tx] = t[tx][ty];
    }
}

// ---------------- GEMM: C(MxN) = A(MxK) * Bt(NxK)^T, bf16 in, f32 acc ----------------
template<int OUTF32>
__global__ __launch_bounds__(256) void k_gemm_bt(const unsigned short* __restrict__ A,
                                                 const unsigned short* __restrict__ Bt,
                                                 void* __restrict__ Cout,
                                                 int M, int N, int K) {
    __shared__ unsigned short As[128][40];
    __shared__ unsigned short Bs[128][40];
    int tid = threadIdx.x;
    int lane = tid & 63;
    int wave = tid >> 6;
    int wm = wave >> 1, wn = wave & 1;
    int lr = lane & 15, lk = (lane >> 4) * 8;
    int sr = tid >> 1, sc = (tid & 1) * 16;
    const unsigned short* Arow = A + (size_t)(blockIdx.x * 128 + sr) * K + sc;
    const unsigned short* Brow = Bt + (size_t)(blockIdx.y * 128 + sr) * K + sc;
    f32x4 acc[4][4] = {};
    for (int k0 = 0; k0 < K; k0 += 32) {
        __syncthreads();
        *(s16x8*)&As[sr][sc]     = *(const s16x8*)(Arow + k0);
        *(s16x8*)&As[sr][sc + 8] = *(const s16x8*)(Arow + k0 + 8);
        *(s16x8*)&Bs[sr][sc]     = *(const s16x8*)(Brow + k0);
        *(s16x8*)&Bs[sr][sc + 8] = *(const s16x8*)(Brow + k0 + 8);
        __syncthreads();
        s16x8 af[4], bfr[4];
        for (int m = 0; m < 4; m++) af[m]  = *(const s16x8*)&As[wm * 64 + m * 16 + lr][lk];
        for (int n = 0; n < 4; n++) bfr[n] = *(const s16x8*)&Bs[wn * 64 + n * 16 + lr][lk];
        for (int m = 0; m < 4; m++)
            for (int n = 0; n < 4; n++)
                acc[m][n] = __builtin_amdgcn_mfma_f32_16x16x32_bf16(af[m], bfr[n], acc[m][n], 0, 0, 0);
    }
    int rbase = blockIdx.x * 128 + wm * 64;
    int cbase = blockIdx.y * 128 + wn * 64;
    for (int m = 0; m < 4; m++)
        for (int n = 0; n < 4; n++)
            for (int r = 0; r < 4; r++) {
                int row = rbase + m * 16 + (lane >> 4) * 4 + r;
                int col = cbase + n * 16 + lr;
                float v = acc[m][n][r];
                if (OUTF32) ((float*)Cout)[(size_t)row * N + col] = v;
                else        ((unsigned short*)Cout)[(size_t)row * N + col] = f2bf(v);
            }
}

// ---------------- fused RMSNorm + RoPE + head transpose ----------------
__global__ __launch_bounds__(256) void k_rms_rope(const unsigned short* __restrict__ qkv,
                                                  const float* __restrict__ qg,
                                                  const float* __restrict__ kg,
                                                  const float* __restrict__ cosc,
                                                  const float* __restrict__ sinc,
                                                  unsigned short* __restrict__ Qt,
                                                  unsigned short* __restrict__ Kt,
                                                  unsigned short* __restrict__ Vt) {
    int r = blockIdx.x;            // b*2048 + s
    int b = r >> 11;
    int s = r & 2047;
    int wave = threadIdx.x >> 6, lane = threadIdx.x & 63;
    const unsigned short* row = qkv + (size_t)r * 4096;
    float c  = cosc[s * 64 + lane];
    float sn = sinc[s * 64 + lane];
    for (int seg = wave; seg < 32; seg += 4) {
        int col0 = seg * 128;
        float e0 = bf2f(row[col0 + lane]);
        float e1 = bf2f(row[col0 + 64 + lane]);
        if (seg < 24) {
            float ss = e0 * e0 + e1 * e1;
            for (int m = 1; m < 64; m <<= 1) ss += __shfl_xor(ss, m, 64);
            float rn = rsqrtf(ss * (1.0f / 128.0f) + 1e-6f);
            const float* g = (seg < 16) ? qg : kg;
            float t0 = e0 * rn * g[lane];
            float t1 = e1 * rn * g[lane + 64];
            float o0 = t0 * c - t1 * sn;
            float o1 = t1 * c + t0 * sn;
            unsigned short* dst;
            if (seg < 16) dst = Qt + ((size_t)(b * 16 + seg) * 2048 + s) * 128;
            else          dst = Kt + ((size_t)(b * 8 + (seg - 16)) * 2048 + s) * 128;
            dst[lane]      = f2bf(o0);
            dst[lane + 64] = f2bf(o1);
        } else {
            unsigned short* dst = Vt + ((size_t)(b * 8 + (seg - 24)) * 2048 + s) * 128;
            dst[lane]      = row[col0 + lane];
            dst[lane + 64] = row[col0 + 64 + lane];
        }
    }
}

// ---------------- causal GQA flash attention ----------------
// 4 waves/block, QBLK=64 (16 rows/wave), KVBLK=64; K + V^T staged in LDS
__global__ __launch_bounds__(256) void k_attn(const unsigned short* __restrict__ Qt,
                                              const unsigned short* __restrict__ Kt,
                                              const unsigned short* __restrict__ Vtg,
                                              unsigned short* __restrict__ attn) {
    __shared__ unsigned short Ks[64][136];     // 17408 B, padded: row stride 272B
    __shared__ unsigned short Vs[128][72];     // 18432 B, padded: row stride 144B (V^T tile: [d][k])
    __shared__ unsigned short Ps[4][16][72];   //  9216 B per-wave P tile
    int qb = blockIdx.x;               // 0..31
    int bh = blockIdx.y;               // b*16 + h
    int b = bh >> 4, h = bh & 15;
    int kvh = h >> 1;
    int tid = threadIdx.x;
    int lane = tid & 63, wave = tid >> 6;
    int lr = lane & 15, lg = lane >> 4;
    int q0 = qb * 64;
    const unsigned short* Qbase = Qt + ((size_t)bh * 2048 + q0 + wave * 16) * 128;
    const unsigned short* Kbase = Kt + (size_t)(b * 8 + kvh) * 2048 * 128;
    const unsigned short* Vtb   = Vtg + (size_t)(b * 8 + kvh) * 128 * 2048;   // [d][s]
    s16x8 aq[4];
    for (int f = 0; f < 4; f++)
        aq[f] = *(const s16x8*)(Qbase + (size_t)lr * 128 + f * 32 + lg * 8);
    f32x4 out[8] = {};
    float m_r[4] = {-1e30f, -1e30f, -1e30f, -1e30f};
    float l_r[4] = {0.f, 0.f, 0.f, 0.f};
    const float scale = 0.08838834764831845f;  // 1/sqrt(128)
    int ntiles = qb + 1;
    for (int t = 0; t < ntiles; t++) {
        int k0 = t * 64;
        __syncthreads();   // previous tile's LDS reads complete
        // stage K tile: 64 rows x 128 cols, coalesced 16B
        for (int p = 0; p < 4; p++) {
            int r = (tid >> 4) + p * 16;
            int c = (tid & 15) * 8;
            *(s16x8*)&Ks[r][c] = *(const s16x8*)(Kbase + (size_t)(k0 + r) * 128 + c);
        }
        // stage V^T tile: 128 d-rows x 64 k-cols
        for (int p = 0; p < 4; p++) {
            int d = (tid >> 3) + p * 32;
            int c = (tid & 7) * 8;
            *(s16x8*)&Vs[d][c] = *(const s16x8*)(Vtb + (size_t)d * 2048 + k0 + c);
        }
        __syncthreads();
        // QK^T: 4 subtiles of 16 cols, K=128
        f32x4 s[4] = {};
        for (int sub = 0; sub < 4; sub++)
            for (int f = 0; f < 4; f++) {
                s16x8 bk = *(const s16x8*)&Ks[sub * 16 + lr][f * 32 + lg * 8];
                s[sub] = __builtin_amdgcn_mfma_f32_16x16x32_bf16(aq[f], bk, s[sub], 0, 0, 0);
            }
        // online softmax, one reduce pair per row over the 64-wide tile
        float sf[4];
        for (int r = 0; r < 4; r++) {
            int qrow = q0 + wave * 16 + lg * 4 + r;
            float v[4];
            for (int sub = 0; sub < 4; sub++)
                v[sub] = (k0 + sub * 16 + lr <= qrow) ? s[sub][r] * scale : -1e30f;
            float mx = fmaxf(fmaxf(v[0], v[1]), fmaxf(v[2], v[3]));
            for (int mk = 1; mk < 16; mk <<= 1) mx = fmaxf(mx, __shfl_xor(mx, mk, 16));
            float mnew = fmaxf(m_r[r], mx);
            sf[r] = __expf(m_r[r] - mnew);
            m_r[r] = mnew;
            float rs = 0.f;
            for (int sub = 0; sub < 4; sub++) {
                float e = __expf(v[sub] - mnew);
                Ps[wave][lg * 4 + r][sub * 16 + lr] = f2bf(e);
                rs += e;
            }
            for (int mk = 1; mk < 16; mk <<= 1) rs += __shfl_xor(rs, mk, 16);
            l_r[r] = l_r[r] * sf[r] + rs;
        }
        for (int blk = 0; blk < 8; blk++)
            for (int r = 0; r < 4; r++) out[blk][r] *= sf[r];
        // PV: P (16x64) x V (64x128)
        for (int ks = 0; ks < 2; ks++) {
            s16x8 ap = *(const s16x8*)&Ps[wave][lr][ks * 32 + lg * 8];
            for (int blk = 0; blk < 8; blk++) {
                s16x8 bv = *(const s16x8*)&Vs[blk * 16 + lr][ks * 32 + lg * 8];
                out[blk] = __builtin_amdgcn_mfma_f32_16x16x32_bf16(ap, bv, out[blk], 0, 0, 0);
            }
        }
    }
    float inv[4];
    for (int r = 0; r < 4; r++) inv[r] = 1.0f / l_r[r];
    for (int blk = 0; blk < 8; blk++)
        for (int r = 0; r < 4; r++) {
            int row = q0 + wave * 16 + lg * 4 + r;
            attn[((size_t)(b * 2048) + row) * 2048 + h * 128 + blk * 16 + lr] =
                f2bf(out[blk][r] * inv[r]);
        }
}

extern "C" void kernel_launch(void* const* d_in, const int* in_sizes, int n_in,
                              void* d_out, int out_size, void* d_ws, size_t ws_size,
                              hipStream_t stream) {
    const float* x    = (const float*)d_in[0];
    const float* wq   = (const float*)d_in[1];
    const float* wk   = (const float*)d_in[2];
    const float* wv   = (const float*)d_in[3];
    const float* wo   = (const float*)d_in[4];
    const float* qg   = (const float*)d_in[5];
    const float* kg   = (const float*)d_in[6];
    const float* cosc = (const float*)d_in[7];
    const float* sinc = (const float*)d_in[8];

    char* ws = (char*)d_ws;
    // workspace layout (bytes); total = 120 MiB
    unsigned short* xb   = (unsigned short*)(ws);                 // 16 MiB  x bf16 (4096x2048)
    unsigned short* w1t  = (unsigned short*)(ws + 16777216);      // 16 MiB  packed [wq|wk|wv]^T (4096x2048)
    unsigned short* w2t  = (unsigned short*)(ws + 33554432);      //  8 MiB  wo^T (2048x2048)
    unsigned short* qkv  = (unsigned short*)(ws + 41943040);      // 32 MiB  (4096x4096); dead after k_rms_rope
    unsigned short* Qt   = (unsigned short*)(ws + 75497472);      // 16 MiB  (2,16,2048,128)
    unsigned short* Kt   = (unsigned short*)(ws + 92274688);      //  8 MiB  (2,8,2048,128)
    unsigned short* Vt   = (unsigned short*)(ws + 100663296);     //  8 MiB  (2,8,2048,128)
    unsigned short* attn = (unsigned short*)(ws + 109051904);     // 16 MiB  (4096x2048)
    unsigned short* Vtg  = qkv;                                   //  8 MiB  (2,8,128,2048) reuses qkv

    k_convert_x<<<4096, 256, 0, stream>>>(x, xb, 8388608);
    k_transpose_w<<<dim3(64, 64), 256, 0, stream>>>(wq, w1t, 2048, 2048, 0, 2048);
    k_transpose_w<<<dim3(64, 32), 256, 0, stream>>>(wk, w1t, 2048, 1024, 2048, 2048);
    k_transpose_w<<<dim3(64, 32), 256, 0, stream>>>(wv, w1t, 2048, 1024, 3072, 2048);
    k_transpose_w<<<dim3(64, 64), 256, 0, stream>>>(wo, w2t, 2048, 2048, 0, 2048);
    k_gemm_bt<0><<<dim3(32, 32), 256, 0, stream>>>(xb, w1t, qkv, 4096, 4096, 2048);
    k_rms_rope<<<4096, 256, 0, stream>>>(qkv, qg, kg, cosc, sinc, Qt, Kt, Vt);
    k_transpose_v<<<dim3(64, 4, 16), 256, 0, stream>>>(Vt, Vtg);
    k_attn<<<dim3(32, 32), 256, 0, stream>>>(Qt, Kt, Vtg, attn);
    k_gemm_bt<1><<<dim3(32, 16), 256, 0, stream>>>(attn, w2t, d_out, 4096, 2048, 2048);
}

// Round 3
// 381.269 us; speedup vs baseline: 1.3616x; 1.3616x over previous
//
#include <hip/hip_runtime.h>
#include <hip/hip_bf16.h>

// Problem constants: B=2, S=2048, DIM=2048, H=16, KVH=8, D=128
// qkv packed columns: [0,2048)=Q (h*128+d), [2048,3072)=K, [3072,4096)=V

typedef __attribute__((ext_vector_type(8))) short s16x8;   // 8 bf16 in 4 VGPRs
typedef __attribute__((ext_vector_type(4))) float f32x4;

static __device__ __forceinline__ unsigned short f2bf(float f) {
    union { float f; unsigned u; } v; v.f = f;
    unsigned r = v.u + 0x7FFF + ((v.u >> 16) & 1);   // RNE
    return (unsigned short)(r >> 16);
}
static __device__ __forceinline__ float bf2f(unsigned short h) {
    union { unsigned u; float f; } v; v.u = ((unsigned)h) << 16;
    return v.f;
}

// ---------------- f32 -> bf16 elementwise convert (x) ----------------
__global__ __launch_bounds__(256) void k_convert_x(const float* __restrict__ x,
                                                   unsigned short* __restrict__ xb, int n) {
    int i = (blockIdx.x * 256 + threadIdx.x) * 8;
    if (i >= n) return;
    float4 a = *(const float4*)(x + i);
    float4 b = *(const float4*)(x + i + 4);
    s16x8 o;
    o[0] = (short)f2bf(a.x); o[1] = (short)f2bf(a.y); o[2] = (short)f2bf(a.z); o[3] = (short)f2bf(a.w);
    o[4] = (short)f2bf(b.x); o[5] = (short)f2bf(b.y); o[6] = (short)f2bf(b.z); o[7] = (short)f2bf(b.w);
    *(s16x8*)(xb + i) = o;
}

// ---------------- weight transpose f32 (K x N) -> bf16 (N x K) ----------------
__global__ __launch_bounds__(256) void k_transpose_w(const float* __restrict__ src,
                                                     unsigned short* __restrict__ dst,
                                                     int K, int N, int nbase, int dstld) {
    __shared__ float t[32][33];
    int k0 = blockIdx.x * 32, n0 = blockIdx.y * 32;
    int tx = threadIdx.x & 31, ty0 = threadIdx.x >> 5;
    for (int p = 0; p < 4; p++) {
        int ty = ty0 + p * 8;
        t[ty][tx] = src[(size_t)(k0 + ty) * N + n0 + tx];
    }
    __syncthreads();
    for (int p = 0; p < 4; p++) {
        int ty = ty0 + p * 8;
        dst[(size_t)(nbase + n0 + ty) * dstld + k0 + tx] = f2bf(t[tx][ty]);
    }
}

// ---------------- bf16 transpose: V (2048 x 128) -> Vt (128 x 2048), per (b,kvh) ----------------
__global__ __launch_bounds__(256) void k_transpose_v(const unsigned short* __restrict__ V,
                                                     unsigned short* __restrict__ Vt) {
    __shared__ unsigned short t[32][33];
    int s0 = blockIdx.x * 32, d0 = blockIdx.y * 32;
    size_t base = (size_t)blockIdx.z * 2048 * 128;
    int tx = threadIdx.x & 31, ty0 = threadIdx.x >> 5;
    for (int p = 0; p < 4; p++) {
        int ty = ty0 + p * 8;
        t[ty][tx] = V[base + (size_t)(s0 + ty) * 128 + d0 + tx];
    }
    __syncthreads();
    for (int p = 0; p < 4; p++) {
        int ty = ty0 + p * 8;
        Vt[base + (size_t)(d0 + ty) * 2048 + s0 + tx] = t[tx][ty];
    }
}

// ---------------- GEMM: C(MxN) = A(MxK) * Bt(NxK)^T, bf16 in, f32 acc ----------------
template<int OUTF32>
__global__ __launch_bounds__(256) void k_gemm_bt(const unsigned short* __restrict__ A,
                                                 const unsigned short* __restrict__ Bt,
                                                 void* __restrict__ Cout,
                                                 int M, int N, int K) {
    __shared__ unsigned short As[128][40];
    __shared__ unsigned short Bs[128][40];
    int tid = threadIdx.x;
    int lane = tid & 63;
    int wave = tid >> 6;
    int wm = wave >> 1, wn = wave & 1;
    int lr = lane & 15, lk = (lane >> 4) * 8;
    int sr = tid >> 1, sc = (tid & 1) * 16;
    const unsigned short* Arow = A + (size_t)(blockIdx.x * 128 + sr) * K + sc;
    const unsigned short* Brow = Bt + (size_t)(blockIdx.y * 128 + sr) * K + sc;
    f32x4 acc[4][4] = {};
    for (int k0 = 0; k0 < K; k0 += 32) {
        __syncthreads();
        *(s16x8*)&As[sr][sc]     = *(const s16x8*)(Arow + k0);
        *(s16x8*)&As[sr][sc + 8] = *(const s16x8*)(Arow + k0 + 8);
        *(s16x8*)&Bs[sr][sc]     = *(const s16x8*)(Brow + k0);
        *(s16x8*)&Bs[sr][sc + 8] = *(const s16x8*)(Brow + k0 + 8);
        __syncthreads();
        s16x8 af[4], bfr[4];
        for (int m = 0; m < 4; m++) af[m]  = *(const s16x8*)&As[wm * 64 + m * 16 + lr][lk];
        for (int n = 0; n < 4; n++) bfr[n] = *(const s16x8*)&Bs[wn * 64 + n * 16 + lr][lk];
        for (int m = 0; m < 4; m++)
            for (int n = 0; n < 4; n++)
                acc[m][n] = __builtin_amdgcn_mfma_f32_16x16x32_bf16(af[m], bfr[n], acc[m][n], 0, 0, 0);
    }
    int rbase = blockIdx.x * 128 + wm * 64;
    int cbase = blockIdx.y * 128 + wn * 64;
    for (int m = 0; m < 4; m++)
        for (int n = 0; n < 4; n++)
            for (int r = 0; r < 4; r++) {
                int row = rbase + m * 16 + (lane >> 4) * 4 + r;
                int col = cbase + n * 16 + lr;
                float v = acc[m][n][r];
                if (OUTF32) ((float*)Cout)[(size_t)row * N + col] = v;
                else        ((unsigned short*)Cout)[(size_t)row * N + col] = f2bf(v);
            }
}

// ---------------- fused RMSNorm + RoPE + head transpose ----------------
__global__ __launch_bounds__(256) void k_rms_rope(const unsigned short* __restrict__ qkv,
                                                  const float* __restrict__ qg,
                                                  const float* __restrict__ kg,
                                                  const float* __restrict__ cosc,
                                                  const float* __restrict__ sinc,
                                                  unsigned short* __restrict__ Qt,
                                                  unsigned short* __restrict__ Kt,
                                                  unsigned short* __restrict__ Vt) {
    int r = blockIdx.x;            // b*2048 + s
    int b = r >> 11;
    int s = r & 2047;
    int wave = threadIdx.x >> 6, lane = threadIdx.x & 63;
    const unsigned short* row = qkv + (size_t)r * 4096;
    float c  = cosc[s * 64 + lane];
    float sn = sinc[s * 64 + lane];
    for (int seg = wave; seg < 32; seg += 4) {
        int col0 = seg * 128;
        float e0 = bf2f(row[col0 + lane]);
        float e1 = bf2f(row[col0 + 64 + lane]);
        if (seg < 24) {
            float ss = e0 * e0 + e1 * e1;
            for (int m = 1; m < 64; m <<= 1) ss += __shfl_xor(ss, m, 64);
            float rn = rsqrtf(ss * (1.0f / 128.0f) + 1e-6f);
            const float* g = (seg < 16) ? qg : kg;
            float t0 = e0 * rn * g[lane];
            float t1 = e1 * rn * g[lane + 64];
            float o0 = t0 * c - t1 * sn;
            float o1 = t1 * c + t0 * sn;
            unsigned short* dst;
            if (seg < 16) dst = Qt + ((size_t)(b * 16 + seg) * 2048 + s) * 128;
            else          dst = Kt + ((size_t)(b * 8 + (seg - 16)) * 2048 + s) * 128;
            dst[lane]      = f2bf(o0);
            dst[lane + 64] = f2bf(o1);
        } else {
            unsigned short* dst = Vt + ((size_t)(b * 8 + (seg - 24)) * 2048 + s) * 128;
            dst[lane]      = row[col0 + lane];
            dst[lane + 64] = row[col0 + 64 + lane];
        }
    }
}

// ---------------- causal GQA flash attention ----------------
// 4 waves/block, QBLK=64 (16 rows/wave), KVBLK=64
// Swapped QK^T (S^T in regs, q = lane&15) -> near-lane-local softmax;
// register prefetch of next K/V tile (async-stage split).
__global__ __launch_bounds__(256) void k_attn(const unsigned short* __restrict__ Qt,
                                              const unsigned short* __restrict__ Kt,
                                              const unsigned short* __restrict__ Vtg,
                                              unsigned short* __restrict__ attn) {
    __shared__ unsigned short Ks[64][136];     // K tile [kv][d], padded
    __shared__ unsigned short Vs[128][72];     // V^T tile [d][kv], padded
    __shared__ unsigned short Ps[4][16][72];   // per-wave P tile [q][kv], padded
    int qb = blockIdx.x;               // 0..31
    int bh = blockIdx.y;               // b*16 + h
    int b = bh >> 4, h = bh & 15;
    int kvh = h >> 1;
    int tid = threadIdx.x;
    int lane = tid & 63, wave = tid >> 6;
    int lr = lane & 15, lg = lane >> 4;
    int q0 = qb * 64;
    const unsigned short* Qbase = Qt + ((size_t)bh * 2048 + q0 + wave * 16) * 128;
    const unsigned short* Kbase = Kt + (size_t)(b * 8 + kvh) * 2048 * 128;
    const unsigned short* Vtb   = Vtg + (size_t)(b * 8 + kvh) * 128 * 2048;   // [d][s]
    s16x8 aq[4];
    #pragma unroll
    for (int f = 0; f < 4; f++)
        aq[f] = *(const s16x8*)(Qbase + (size_t)lr * 128 + f * 32 + lg * 8);
    f32x4 out[8] = {};
    float m_q = -1e30f;                // running max for q = q0+wave*16+lr (dup across lg)
    float l_q = 0.f;
    int qglob = q0 + wave * 16 + lr;
    const float scale = 0.08838834764831845f;  // 1/sqrt(128)
    int ntiles = qb + 1;
    // staging coords
    int krow = tid >> 4, kcol = (tid & 15) * 8;   // K tile: 16 rows x 128 cols per pass
    int vrow = tid >> 3, vcol = (tid & 7) * 8;    // V^T tile: 32 rows x 64 cols per pass
    s16x8 kpre[4], vpre[4];
    #pragma unroll
    for (int p = 0; p < 4; p++) {
        kpre[p] = *(const s16x8*)(Kbase + (size_t)(krow + p * 16) * 128 + kcol);
        vpre[p] = *(const s16x8*)(Vtb + (size_t)(vrow + p * 32) * 2048 + vcol);
    }
    for (int t = 0; t < ntiles; t++) {
        int k0 = t * 64;
        __syncthreads();   // previous tile's LDS reads complete
        #pragma unroll
        for (int p = 0; p < 4; p++) *(s16x8*)&Ks[krow + p * 16][kcol] = kpre[p];
        #pragma unroll
        for (int p = 0; p < 4; p++) *(s16x8*)&Vs[vrow + p * 32][vcol] = vpre[p];
        __syncthreads();
        if (t + 1 < ntiles) {
            int kn = k0 + 64;
            #pragma unroll
            for (int p = 0; p < 4; p++) {
                kpre[p] = *(const s16x8*)(Kbase + (size_t)(kn + krow + p * 16) * 128 + kcol);
                vpre[p] = *(const s16x8*)(Vtb + (size_t)(vrow + p * 32) * 2048 + kn + vcol);
            }
        }
        // swapped QK^T: S^T[kv][q], A-frag = K rows, B-frag = Q
        f32x4 st[4] = {};
        #pragma unroll
        for (int sub = 0; sub < 4; sub++)
            #pragma unroll
            for (int f = 0; f < 4; f++) {
                s16x8 bk = *(const s16x8*)&Ks[sub * 16 + lr][f * 32 + lg * 8];
                st[sub] = __builtin_amdgcn_mfma_f32_16x16x32_bf16(bk, aq[f], st[sub], 0, 0, 0);
            }
        // softmax: lane holds 16 values of row q=qglob at kv = k0 + sub*16 + lg*4 + r
        float pv[16];
        float mx = -1e30f;
        #pragma unroll
        for (int sub = 0; sub < 4; sub++)
            #pragma unroll
            for (int r = 0; r < 4; r++) {
                int kv = k0 + sub * 16 + lg * 4 + r;
                float v = (kv <= qglob) ? st[sub][r] * scale : -1e30f;
                pv[sub * 4 + r] = v;
                mx = fmaxf(mx, v);
            }
        mx = fmaxf(mx, __shfl_xor(mx, 16, 64));
        mx = fmaxf(mx, __shfl_xor(mx, 32, 64));
        float mnew = fmaxf(m_q, mx);
        float sf = __expf(m_q - mnew);
        m_q = mnew;
        float rs = 0.f;
        #pragma unroll
        for (int i = 0; i < 16; i++) { float e = __expf(pv[i] - mnew); pv[i] = e; rs += e; }
        rs += __shfl_xor(rs, 16, 64);
        rs += __shfl_xor(rs, 32, 64);
        l_q = l_q * sf + rs;
        // pack P -> Ps[q][kv], vectorized b64 writes
        #pragma unroll
        for (int sub = 0; sub < 4; sub++) {
            unsigned lo = (unsigned)f2bf(pv[sub * 4 + 0]) | ((unsigned)f2bf(pv[sub * 4 + 1]) << 16);
            unsigned hi = (unsigned)f2bf(pv[sub * 4 + 2]) | ((unsigned)f2bf(pv[sub * 4 + 3]) << 16);
            uint2 w; w.x = lo; w.y = hi;
            *(uint2*)&Ps[wave][lr][sub * 16 + lg * 4] = w;
        }
        // rescale accumulator (per out row q = lg*4 + r)
        float sfr[4];
        #pragma unroll
        for (int r = 0; r < 4; r++) sfr[r] = __shfl(sf, lg * 4 + r, 64);
        #pragma unroll
        for (int blk = 0; blk < 8; blk++)
            #pragma unroll
            for (int r = 0; r < 4; r++) out[blk][r] *= sfr[r];
        // PV: P (16x64) x V^T tile
        #pragma unroll
        for (int ks = 0; ks < 2; ks++) {
            s16x8 ap = *(const s16x8*)&Ps[wave][lr][ks * 32 + lg * 8];
            #pragma unroll
            for (int blk = 0; blk < 8; blk++) {
                s16x8 bv = *(const s16x8*)&Vs[blk * 16 + lr][ks * 32 + lg * 8];
                out[blk] = __builtin_amdgcn_mfma_f32_16x16x32_bf16(ap, bv, out[blk], 0, 0, 0);
            }
        }
    }
    float linv = 1.0f / l_q;
    float inv[4];
    #pragma unroll
    for (int r = 0; r < 4; r++) inv[r] = __shfl(linv, lg * 4 + r, 64);
    #pragma unroll
    for (int blk = 0; blk < 8; blk++)
        #pragma unroll
        for (int r = 0; r < 4; r++) {
            int row = q0 + wave * 16 + lg * 4 + r;
            attn[((size_t)(b * 2048) + row) * 2048 + h * 128 + blk * 16 + lr] =
                f2bf(out[blk][r] * inv[r]);
        }
}

extern "C" void kernel_launch(void* const* d_in, const int* in_sizes, int n_in,
                              void* d_out, int out_size, void* d_ws, size_t ws_size,
                              hipStream_t stream) {
    const float* x    = (const float*)d_in[0];
    const float* wq   = (const float*)d_in[1];
    const float* wk   = (const float*)d_in[2];
    const float* wv   = (const float*)d_in[3];
    const float* wo   = (const float*)d_in[4];
    const float* qg   = (const float*)d_in[5];
    const float* kg   = (const float*)d_in[6];
    const float* cosc = (const float*)d_in[7];
    const float* sinc = (const float*)d_in[8];

    char* ws = (char*)d_ws;
    // workspace layout (bytes); total = 120 MiB
    unsigned short* xb   = (unsigned short*)(ws);                 // 16 MiB  x bf16 (4096x2048)
    unsigned short* w1t  = (unsigned short*)(ws + 16777216);      // 16 MiB  packed [wq|wk|wv]^T (4096x2048)
    unsigned short* w2t  = (unsigned short*)(ws + 33554432);      //  8 MiB  wo^T (2048x2048)
    unsigned short* qkv  = (unsigned short*)(ws + 41943040);      // 32 MiB  (4096x4096); dead after k_rms_rope
    unsigned short* Qt   = (unsigned short*)(ws + 75497472);      // 16 MiB  (2,16,2048,128)
    unsigned short* Kt   = (unsigned short*)(ws + 92274688);      //  8 MiB  (2,8,2048,128)
    unsigned short* Vt   = (unsigned short*)(ws + 100663296);     //  8 MiB  (2,8,2048,128)
    unsigned short* attn = (unsigned short*)(ws + 109051904);     // 16 MiB  (4096x2048)
    unsigned short* Vtg  = qkv;                                   //  8 MiB  (2,8,128,2048) reuses qkv

    k_convert_x<<<4096, 256, 0, stream>>>(x, xb, 8388608);
    k_transpose_w<<<dim3(64, 64), 256, 0, stream>>>(wq, w1t, 2048, 2048, 0, 2048);
    k_transpose_w<<<dim3(64, 32), 256, 0, stream>>>(wk, w1t, 2048, 1024, 2048, 2048);
    k_transpose_w<<<dim3(64, 32), 256, 0, stream>>>(wv, w1t, 2048, 1024, 3072, 2048);
    k_transpose_w<<<dim3(64, 64), 256, 0, stream>>>(wo, w2t, 2048, 2048, 0, 2048);
    k_gemm_bt<0><<<dim3(32, 32), 256, 0, stream>>>(xb, w1t, qkv, 4096, 4096, 2048);
    k_rms_rope<<<4096, 256, 0, stream>>>(qkv, qg, kg, cosc, sinc, Qt, Kt, Vt);
    k_transpose_v<<<dim3(64, 4, 16), 256, 0, stream>>>(Vt, Vtg);
    k_attn<<<dim3(32, 32), 256, 0, stream>>>(Qt, Kt, Vtg, attn);
    k_gemm_bt<1><<<dim3(32, 16), 256, 0, stream>>>(attn, w2t, d_out, 4096, 2048, 2048);
}

// Round 4
// 334.818 us; speedup vs baseline: 1.5506x; 1.1387x over previous
//
#include <hip/hip_runtime.h>
#include <hip/hip_bf16.h>

// Problem constants: B=2, S=2048, DIM=2048, H=16, KVH=8, D=128

typedef __attribute__((ext_vector_type(8))) short s16x8;   // 8 bf16 in 4 VGPRs
typedef __attribute__((ext_vector_type(4))) float f32x4;

typedef const __attribute__((address_space(1))) void* gas_t;
typedef __attribute__((address_space(3))) void* las_t;
#define GLL16(g, l) __builtin_amdgcn_global_load_lds((gas_t)(const void*)(g), (las_t)(void*)(l), 16, 0, 0)

static __device__ __forceinline__ unsigned short f2bf(float f) {
    union { float f; unsigned u; } v; v.f = f;
    unsigned r = v.u + 0x7FFF + ((v.u >> 16) & 1);   // RNE
    return (unsigned short)(r >> 16);
}
static __device__ __forceinline__ float bf2f(unsigned short h) {
    union { unsigned u; float f; } v; v.u = ((unsigned)h) << 16;
    return v.f;
}

// ---------------- f32 -> bf16 elementwise convert (x) ----------------
__global__ __launch_bounds__(256) void k_convert_x(const float* __restrict__ x,
                                                   unsigned short* __restrict__ xb, int n) {
    int i = (blockIdx.x * 256 + threadIdx.x) * 8;
    if (i >= n) return;
    float4 a = *(const float4*)(x + i);
    float4 b = *(const float4*)(x + i + 4);
    s16x8 o;
    o[0] = (short)f2bf(a.x); o[1] = (short)f2bf(a.y); o[2] = (short)f2bf(a.z); o[3] = (short)f2bf(a.w);
    o[4] = (short)f2bf(b.x); o[5] = (short)f2bf(b.y); o[6] = (short)f2bf(b.z); o[7] = (short)f2bf(b.w);
    *(s16x8*)(xb + i) = o;
}

// ---------------- weight transpose f32 (K x N) -> bf16 (N x K) ----------------
__global__ __launch_bounds__(256) void k_transpose_w(const float* __restrict__ src,
                                                     unsigned short* __restrict__ dst,
                                                     int K, int N, int nbase, int dstld) {
    __shared__ float t[32][33];
    int k0 = blockIdx.x * 32, n0 = blockIdx.y * 32;
    int tx = threadIdx.x & 31, ty0 = threadIdx.x >> 5;
    for (int p = 0; p < 4; p++) {
        int ty = ty0 + p * 8;
        t[ty][tx] = src[(size_t)(k0 + ty) * N + n0 + tx];
    }
    __syncthreads();
    for (int p = 0; p < 4; p++) {
        int ty = ty0 + p * 8;
        dst[(size_t)(nbase + n0 + ty) * dstld + k0 + tx] = f2bf(t[tx][ty]);
    }
}

// ---------------- bf16 transpose: V (2048 x 128) -> Vt (128 x 2048), per (b,kvh) ----------------
__global__ __launch_bounds__(256) void k_transpose_v(const unsigned short* __restrict__ V,
                                                     unsigned short* __restrict__ Vt) {
    __shared__ unsigned short t[32][33];
    int s0 = blockIdx.x * 32, d0 = blockIdx.y * 32;
    size_t base = (size_t)blockIdx.z * 2048 * 128;
    int tx = threadIdx.x & 31, ty0 = threadIdx.x >> 5;
    for (int p = 0; p < 4; p++) {
        int ty = ty0 + p * 8;
        t[ty][tx] = V[base + (size_t)(s0 + ty) * 128 + d0 + tx];
    }
    __syncthreads();
    for (int p = 0; p < 4; p++) {
        int ty = ty0 + p * 8;
        Vt[base + (size_t)(d0 + ty) * 2048 + s0 + tx] = t[tx][ty];
    }
}

// ---------------- GEMM: C(MxN) = A(MxK) * Bt(NxK)^T, bf16 in, f32 acc ----------------
// m97 structure: 128x128 tile, 4 waves, BK=32, global_load_lds width=16, linear LDS
template<int OUTF32>
__global__ __launch_bounds__(256) void k_gemm_bt(const unsigned short* __restrict__ A,
                                                 const unsigned short* __restrict__ Bt,
                                                 void* __restrict__ Cout,
                                                 int M, int N, int K) {
    __shared__ unsigned short As[128 * 32];
    __shared__ unsigned short Bs[128 * 32];
    int tid = threadIdx.x;
    int lane = tid & 63;
    int wave = tid >> 6;
    int wm = wave >> 1, wn = wave & 1;
    int lr = lane & 15, lk = (lane >> 4) * 8;
    // staging: wave w covers rows [w*32, w*32+32); lane l -> row +i*16+(l>>2), col (l&3)*8
    int srow = wave * 32 + (lane >> 2);
    int scol = (lane & 3) * 8;
    const unsigned short* Ag0 = A  + (size_t)(blockIdx.x * 128 + srow) * K + scol;
    const unsigned short* Ag1 = Ag0 + (size_t)16 * K;
    const unsigned short* Bg0 = Bt + (size_t)(blockIdx.y * 128 + srow) * K + scol;
    const unsigned short* Bg1 = Bg0 + (size_t)16 * K;
    unsigned short* Asw = &As[wave * 1024];   // wave-uniform LDS base
    unsigned short* Bsw = &Bs[wave * 1024];
    f32x4 acc[4][4] = {};
    for (int k0 = 0; k0 < K; k0 += 32) {
        __syncthreads();
        GLL16(Ag0 + k0, Asw);
        GLL16(Ag1 + k0, Asw + 512);
        GLL16(Bg0 + k0, Bsw);
        GLL16(Bg1 + k0, Bsw + 512);
        __syncthreads();
        s16x8 af[4], bfr[4];
        #pragma unroll
        for (int m = 0; m < 4; m++) af[m]  = *(const s16x8*)&As[(wm * 64 + m * 16 + lr) * 32 + lk];
        #pragma unroll
        for (int n = 0; n < 4; n++) bfr[n] = *(const s16x8*)&Bs[(wn * 64 + n * 16 + lr) * 32 + lk];
        #pragma unroll
        for (int m = 0; m < 4; m++)
            #pragma unroll
            for (int n = 0; n < 4; n++)
                acc[m][n] = __builtin_amdgcn_mfma_f32_16x16x32_bf16(af[m], bfr[n], acc[m][n], 0, 0, 0);
    }
    int rbase = blockIdx.x * 128 + wm * 64;
    int cbase = blockIdx.y * 128 + wn * 64;
    #pragma unroll
    for (int m = 0; m < 4; m++)
        #pragma unroll
        for (int n = 0; n < 4; n++)
            #pragma unroll
            for (int r = 0; r < 4; r++) {
                int row = rbase + m * 16 + (lane >> 4) * 4 + r;
                int col = cbase + n * 16 + lr;
                float v = acc[m][n][r];
                if (OUTF32) ((float*)Cout)[(size_t)row * N + col] = v;
                else        ((unsigned short*)Cout)[(size_t)row * N + col] = f2bf(v);
            }
}

// ---------------- fused RMSNorm + RoPE + head transpose ----------------
__global__ __launch_bounds__(256) void k_rms_rope(const unsigned short* __restrict__ qkv,
                                                  const float* __restrict__ qg,
                                                  const float* __restrict__ kg,
                                                  const float* __restrict__ cosc,
                                                  const float* __restrict__ sinc,
                                                  unsigned short* __restrict__ Qt,
                                                  unsigned short* __restrict__ Kt,
                                                  unsigned short* __restrict__ Vt) {
    int r = blockIdx.x;            // b*2048 + s
    int b = r >> 11;
    int s = r & 2047;
    int wave = threadIdx.x >> 6, lane = threadIdx.x & 63;
    const unsigned short* row = qkv + (size_t)r * 4096;
    float c  = cosc[s * 64 + lane];
    float sn = sinc[s * 64 + lane];
    for (int seg = wave; seg < 32; seg += 4) {
        int col0 = seg * 128;
        float e0 = bf2f(row[col0 + lane]);
        float e1 = bf2f(row[col0 + 64 + lane]);
        if (seg < 24) {
            float ss = e0 * e0 + e1 * e1;
            for (int m = 1; m < 64; m <<= 1) ss += __shfl_xor(ss, m, 64);
            float rn = rsqrtf(ss * (1.0f / 128.0f) + 1e-6f);
            const float* g = (seg < 16) ? qg : kg;
            float t0 = e0 * rn * g[lane];
            float t1 = e1 * rn * g[lane + 64];
            float o0 = t0 * c - t1 * sn;
            float o1 = t1 * c + t0 * sn;
            unsigned short* dst;
            if (seg < 16) dst = Qt + ((size_t)(b * 16 + seg) * 2048 + s) * 128;
            else          dst = Kt + ((size_t)(b * 8 + (seg - 16)) * 2048 + s) * 128;
            dst[lane]      = f2bf(o0);
            dst[lane + 64] = f2bf(o1);
        } else {
            unsigned short* dst = Vt + ((size_t)(b * 8 + (seg - 24)) * 2048 + s) * 128;
            dst[lane]      = row[col0 + lane];
            dst[lane + 64] = row[col0 + 64 + lane];
        }
    }
}

// ---------------- causal GQA flash attention ----------------
// 4 waves/block, QBLK=128 (two 16-row fragments per wave), KVBLK=64
// Swapped QK^T (S^T in regs, q = lane&15) -> near-lane-local softmax;
// register prefetch of next K/V tile; duration-balanced block swizzle.
__global__ __launch_bounds__(256) void k_attn(const unsigned short* __restrict__ Qt,
                                              const unsigned short* __restrict__ Kt,
                                              const unsigned short* __restrict__ Vtg,
                                              unsigned short* __restrict__ attn) {
    __shared__ unsigned short Ks[64][136];     // K tile [kv][d], padded
    __shared__ unsigned short Vs[128][72];     // V^T tile [d][kv], padded
    __shared__ unsigned short Ps[4][16][72];   // per-wave P tile [q][kv], padded
    // duration-balanced swizzle: block bid and bid+256 have complementary qb
    int bid = blockIdx.x;                  // 0..511
    int lo = bid & 255;
    int qb, bh;
    if (bid < 256) { qb = lo & 15;        bh = lo >> 4; }
    else           { qb = 15 - (lo & 15); bh = 16 + (lo >> 4); }
    int b = bh >> 4, h = bh & 15;
    int kvh = h >> 1;
    int tid = threadIdx.x;
    int lane = tid & 63, wave = tid >> 6;
    int lr = lane & 15, lg = lane >> 4;
    int q0 = qb * 128;
    const unsigned short* Qb1 = Qt + ((size_t)bh * 2048 + q0 + wave * 16) * 128;
    const unsigned short* Qb2 = Qb1 + (size_t)64 * 128;
    const unsigned short* Kbase = Kt + (size_t)(b * 8 + kvh) * 2048 * 128;
    const unsigned short* Vtb   = Vtg + (size_t)(b * 8 + kvh) * 128 * 2048;   // [d][s]
    s16x8 aq1[4], aq2[4];
    #pragma unroll
    for (int f = 0; f < 4; f++) {
        aq1[f] = *(const s16x8*)(Qb1 + (size_t)lr * 128 + f * 32 + lg * 8);
        aq2[f] = *(const s16x8*)(Qb2 + (size_t)lr * 128 + f * 32 + lg * 8);
    }
    f32x4 o1[8] = {}, o2[8] = {};
    float m1 = -1e30f, l1 = 0.f, m2 = -1e30f, l2 = 0.f;
    int qg1 = q0 + wave * 16 + lr;
    int qg2 = qg1 + 64;
    const float scale = 0.08838834764831845f;  // 1/sqrt(128)
    int ntiles = 2 * qb + 2;
    // staging coords
    int krow = tid >> 4, kcol = (tid & 15) * 8;   // K tile: 16 rows x 128 cols per pass
    int vrow = tid >> 3, vcol = (tid & 7) * 8;    // V^T tile: 32 rows x 64 cols per pass
    s16x8 kpre[4], vpre[4];
    #pragma unroll
    for (int p = 0; p < 4; p++) {
        kpre[p] = *(const s16x8*)(Kbase + (size_t)(krow + p * 16) * 128 + kcol);
        vpre[p] = *(const s16x8*)(Vtb + (size_t)(vrow + p * 32) * 2048 + vcol);
    }

    auto process = [&](const s16x8* aq, int qglob, float& m_q, float& l_q, f32x4* out, int k0) {
        // swapped QK^T: S^T[kv][q], A-frag = K rows, B-frag = Q
        f32x4 st[4] = {};
        __builtin_amdgcn_s_setprio(1);
        #pragma unroll
        for (int sub = 0; sub < 4; sub++)
            #pragma unroll
            for (int f = 0; f < 4; f++) {
                s16x8 bk = *(const s16x8*)&Ks[sub * 16 + lr][f * 32 + lg * 8];
                st[sub] = __builtin_amdgcn_mfma_f32_16x16x32_bf16(bk, aq[f], st[sub], 0, 0, 0);
            }
        __builtin_amdgcn_s_setprio(0);
        // softmax: lane holds 16 values of row q=qglob at kv = k0 + sub*16 + lg*4 + r
        float pv[16];
        float mx = -1e30f;
        #pragma unroll
        for (int sub = 0; sub < 4; sub++)
            #pragma unroll
            for (int r = 0; r < 4; r++) {
                int kv = k0 + sub * 16 + lg * 4 + r;
                float v = (kv <= qglob) ? st[sub][r] * scale : -1e30f;
                pv[sub * 4 + r] = v;
                mx = fmaxf(mx, v);
            }
        mx = fmaxf(mx, __shfl_xor(mx, 16, 64));
        mx = fmaxf(mx, __shfl_xor(mx, 32, 64));
        float mnew = fmaxf(m_q, mx);
        float sf = __expf(m_q - mnew);
        m_q = mnew;
        float rs = 0.f;
        #pragma unroll
        for (int i = 0; i < 16; i++) { float e = __expf(pv[i] - mnew); pv[i] = e; rs += e; }
        rs += __shfl_xor(rs, 16, 64);
        rs += __shfl_xor(rs, 32, 64);
        l_q = l_q * sf + rs;
        // pack P -> Ps[q][kv], vectorized b64 writes
        #pragma unroll
        for (int sub = 0; sub < 4; sub++) {
            unsigned lop = (unsigned)f2bf(pv[sub * 4 + 0]) | ((unsigned)f2bf(pv[sub * 4 + 1]) << 16);
            unsigned hip_ = (unsigned)f2bf(pv[sub * 4 + 2]) | ((unsigned)f2bf(pv[sub * 4 + 3]) << 16);
            uint2 w; w.x = lop; w.y = hip_;
            *(uint2*)&Ps[wave][lr][sub * 16 + lg * 4] = w;
        }
        // rescale accumulator (per out row q = lg*4 + r)
        float sfr[4];
        #pragma unroll
        for (int r = 0; r < 4; r++) sfr[r] = __shfl(sf, lg * 4 + r, 64);
        #pragma unroll
        for (int blk = 0; blk < 8; blk++)
            #pragma unroll
            for (int r = 0; r < 4; r++) out[blk][r] *= sfr[r];
        // PV: P (16x64) x V^T tile
        __builtin_amdgcn_s_setprio(1);
        #pragma unroll
        for (int ks = 0; ks < 2; ks++) {
            s16x8 ap = *(const s16x8*)&Ps[wave][lr][ks * 32 + lg * 8];
            #pragma unroll
            for (int blk = 0; blk < 8; blk++) {
                s16x8 bv = *(const s16x8*)&Vs[blk * 16 + lr][ks * 32 + lg * 8];
                out[blk] = __builtin_amdgcn_mfma_f32_16x16x32_bf16(ap, bv, out[blk], 0, 0, 0);
            }
        }
        __builtin_amdgcn_s_setprio(0);
    };

    for (int t = 0; t < ntiles; t++) {
        int k0 = t * 64;
        __syncthreads();   // previous tile's LDS reads complete
        #pragma unroll
        for (int p = 0; p < 4; p++) *(s16x8*)&Ks[krow + p * 16][kcol] = kpre[p];
        #pragma unroll
        for (int p = 0; p < 4; p++) *(s16x8*)&Vs[vrow + p * 32][vcol] = vpre[p];
        __syncthreads();
        if (t + 1 < ntiles) {
            int kn = k0 + 64;
            #pragma unroll
            for (int p = 0; p < 4; p++) {
                kpre[p] = *(const s16x8*)(Kbase + (size_t)(kn + krow + p * 16) * 128 + kcol);
                vpre[p] = *(const s16x8*)(Vtb + (size_t)(vrow + p * 32) * 2048 + kn + vcol);
            }
        }
        process(aq2, qg2, m2, l2, o2, k0);          // frag2: rows q0+64..q0+127, active all tiles
        if (k0 <= q0 + 63)                           // frag1 fully masked only on the last tile
            process(aq1, qg1, m1, l1, o1, k0);
    }
    float li1 = 1.0f / l1, li2 = 1.0f / l2;
    float inv1[4], inv2[4];
    #pragma unroll
    for (int r = 0; r < 4; r++) {
        inv1[r] = __shfl(li1, lg * 4 + r, 64);
        inv2[r] = __shfl(li2, lg * 4 + r, 64);
    }
    #pragma unroll
    for (int blk = 0; blk < 8; blk++)
        #pragma unroll
        for (int r = 0; r < 4; r++) {
            int row1 = q0 + wave * 16 + lg * 4 + r;
            attn[((size_t)(b * 2048) + row1) * 2048 + h * 128 + blk * 16 + lr] =
                f2bf(o1[blk][r] * inv1[r]);
            attn[((size_t)(b * 2048) + row1 + 64) * 2048 + h * 128 + blk * 16 + lr] =
                f2bf(o2[blk][r] * inv2[r]);
        }
}

extern "C" void kernel_launch(void* const* d_in, const int* in_sizes, int n_in,
                              void* d_out, int out_size, void* d_ws, size_t ws_size,
                              hipStream_t stream) {
    const float* x    = (const float*)d_in[0];
    const float* wq   = (const float*)d_in[1];
    const float* wk   = (const float*)d_in[2];
    const float* wv   = (const float*)d_in[3];
    const float* wo   = (const float*)d_in[4];
    const float* qg   = (const float*)d_in[5];
    const float* kg   = (const float*)d_in[6];
    const float* cosc = (const float*)d_in[7];
    const float* sinc = (const float*)d_in[8];

    char* ws = (char*)d_ws;
    // workspace layout (bytes); total = 120 MiB
    unsigned short* xb   = (unsigned short*)(ws);                 // 16 MiB  x bf16 (4096x2048)
    unsigned short* w1t  = (unsigned short*)(ws + 16777216);      // 16 MiB  packed [wq|wk|wv]^T (4096x2048)
    unsigned short* w2t  = (unsigned short*)(ws + 33554432);      //  8 MiB  wo^T (2048x2048)
    unsigned short* qkv  = (unsigned short*)(ws + 41943040);      // 32 MiB  (4096x4096); dead after k_rms_rope
    unsigned short* Qt   = (unsigned short*)(ws + 75497472);      // 16 MiB  (2,16,2048,128)
    unsigned short* Kt   = (unsigned short*)(ws + 92274688);      //  8 MiB  (2,8,2048,128)
    unsigned short* Vt   = (unsigned short*)(ws + 100663296);     //  8 MiB  (2,8,2048,128)
    unsigned short* attn = (unsigned short*)(ws + 109051904);     // 16 MiB  (4096x2048)
    unsigned short* Vtg  = qkv;                                   //  8 MiB  (2,8,128,2048) reuses qkv

    k_convert_x<<<4096, 256, 0, stream>>>(x, xb, 8388608);
    k_transpose_w<<<dim3(64, 64), 256, 0, stream>>>(wq, w1t, 2048, 2048, 0, 2048);
    k_transpose_w<<<dim3(64, 32), 256, 0, stream>>>(wk, w1t, 2048, 1024, 2048, 2048);
    k_transpose_w<<<dim3(64, 32), 256, 0, stream>>>(wv, w1t, 2048, 1024, 3072, 2048);
    k_transpose_w<<<dim3(64, 64), 256, 0, stream>>>(wo, w2t, 2048, 2048, 0, 2048);
    k_gemm_bt<0><<<dim3(32, 32), 256, 0, stream>>>(xb, w1t, qkv, 4096, 4096, 2048);
    k_rms_rope<<<4096, 256, 0, stream>>>(qkv, qg, kg, cosc, sinc, Qt, Kt, Vt);
    k_transpose_v<<<dim3(64, 4, 16), 256, 0, stream>>>(Vt, Vtg);
    k_attn<<<512, 256, 0, stream>>>(Qt, Kt, Vtg, attn);
    k_gemm_bt<1><<<dim3(32, 16), 256, 0, stream>>>(attn, w2t, d_out, 4096, 2048, 2048);
}

// Round 5
// 304.382 us; speedup vs baseline: 1.7056x; 1.1000x over previous
//
#include <hip/hip_runtime.h>
#include <hip/hip_bf16.h>

// Problem constants: B=2, S=2048, DIM=2048, H=16, KVH=8, D=128

typedef __attribute__((ext_vector_type(8))) short s16x8;   // 8 bf16 in 4 VGPRs
typedef __attribute__((ext_vector_type(4))) float f32x4;

typedef const __attribute__((address_space(1))) void* gas_t;
typedef __attribute__((address_space(3))) void* las_t;
#define GLL16(g, l) __builtin_amdgcn_global_load_lds((gas_t)(const void*)(g), (las_t)(void*)(l), 16, 0, 0)

static __device__ __forceinline__ unsigned short f2bf(float f) {
    union { float f; unsigned u; } v; v.f = f;
    unsigned r = v.u + 0x7FFF + ((v.u >> 16) & 1);   // RNE
    return (unsigned short)(r >> 16);
}
static __device__ __forceinline__ float bf2f(unsigned short h) {
    union { unsigned u; float f; } v; v.u = ((unsigned)h) << 16;
    return v.f;
}

// ---------------- f32 -> bf16 elementwise convert (x) ----------------
__global__ __launch_bounds__(256) void k_convert_x(const float* __restrict__ x,
                                                   unsigned short* __restrict__ xb, int n) {
    int i = (blockIdx.x * 256 + threadIdx.x) * 8;
    if (i >= n) return;
    float4 a = *(const float4*)(x + i);
    float4 b = *(const float4*)(x + i + 4);
    s16x8 o;
    o[0] = (short)f2bf(a.x); o[1] = (short)f2bf(a.y); o[2] = (short)f2bf(a.z); o[3] = (short)f2bf(a.w);
    o[4] = (short)f2bf(b.x); o[5] = (short)f2bf(b.y); o[6] = (short)f2bf(b.z); o[7] = (short)f2bf(b.w);
    *(s16x8*)(xb + i) = o;
}

// ---------------- weight transpose f32 (K x N) -> bf16 (N x K) ----------------
__global__ __launch_bounds__(256) void k_transpose_w(const float* __restrict__ src,
                                                     unsigned short* __restrict__ dst,
                                                     int K, int N, int nbase, int dstld) {
    __shared__ float t[32][33];
    int k0 = blockIdx.x * 32, n0 = blockIdx.y * 32;
    int tx = threadIdx.x & 31, ty0 = threadIdx.x >> 5;
    for (int p = 0; p < 4; p++) {
        int ty = ty0 + p * 8;
        t[ty][tx] = src[(size_t)(k0 + ty) * N + n0 + tx];
    }
    __syncthreads();
    for (int p = 0; p < 4; p++) {
        int ty = ty0 + p * 8;
        dst[(size_t)(nbase + n0 + ty) * dstld + k0 + tx] = f2bf(t[tx][ty]);
    }
}

// ---------------- bf16 transpose: V (2048 x 128) -> Vt (128 x 2048), per (b,kvh) ----------------
__global__ __launch_bounds__(256) void k_transpose_v(const unsigned short* __restrict__ V,
                                                     unsigned short* __restrict__ Vt) {
    __shared__ unsigned short t[32][33];
    int s0 = blockIdx.x * 32, d0 = blockIdx.y * 32;
    size_t base = (size_t)blockIdx.z * 2048 * 128;
    int tx = threadIdx.x & 31, ty0 = threadIdx.x >> 5;
    for (int p = 0; p < 4; p++) {
        int ty = ty0 + p * 8;
        t[ty][tx] = V[base + (size_t)(s0 + ty) * 128 + d0 + tx];
    }
    __syncthreads();
    for (int p = 0; p < 4; p++) {
        int ty = ty0 + p * 8;
        Vt[base + (size_t)(d0 + ty) * 2048 + s0 + tx] = t[tx][ty];
    }
}

// ---------------- 8-phase 256x256 GEMM: C = A(MxK) * Bt(NxK)^T ----------------
// 512 thr (8 waves 2Mx4N), BK=64, dbuf LDS 128KiB, GLL staging with XOR-swizzle
// (pre-swizzled global source + swizzled ds_read), counted vmcnt(2), raw barriers.
template<int OUTF32>
__global__ __launch_bounds__(512, 2) void k_gemm256(const unsigned short* __restrict__ A,
                                                    const unsigned short* __restrict__ Bt,
                                                    void* __restrict__ Cout,
                                                    int M, int N, int K) {
    __shared__ unsigned short As[2][256 * 64];
    __shared__ unsigned short Bs[2][256 * 64];
    int tid = threadIdx.x, lane = tid & 63, wave = tid >> 6;
    int wm = wave >> 2, wn = wave & 3;
    int lr = lane & 15, lg = lane >> 4;
    // staging: round j covers rows j*64..+63; thread (wave,lane) -> row wave*8+(lane>>3)
    // source col pre-swizzled so that LDS (linear dest) image is the swizzled layout
    int srow = wave * 8 + (lane >> 3);
    int scol = (((lane & 7) ^ (lane >> 3)) * 8);
    const unsigned short* Ag = A  + (size_t)(blockIdx.x * 256 + srow) * K + scol;
    const unsigned short* Bg = Bt + (size_t)(blockIdx.y * 256 + srow) * K + scol;
    int ldsoff = wave * 512;   // elements; + j*4096 per round

    f32x4 acc[8][4] = {};
    int NK = K / 64;
    // prologue: stage tile 0 into slot 0 (4 A/B pairs)
    #pragma unroll
    for (int p = 0; p < 4; p++) {
        GLL16(Ag + (size_t)p * 64 * K, &As[0][p * 4096 + ldsoff]);
        GLL16(Bg + (size_t)p * 64 * K, &Bs[0][p * 4096 + ldsoff]);
    }
    for (int t = 0; t < NK; ++t) {
        int slot = t & 1, nslot = slot ^ 1;
        size_t kn = (size_t)(t + 1) * 64;
        bool more = (t + 1) < NK;
        if (more) {   // pair #1 for t+1 (slot freed by previous tile's last barrier)
            GLL16(Ag + kn, &As[nslot][ldsoff]);
            GLL16(Bg + kn, &Bs[nslot][ldsoff]);
            asm volatile("s_waitcnt vmcnt(2)" ::: "memory");
        } else {
            asm volatile("s_waitcnt vmcnt(0)" ::: "memory");
        }
        __builtin_amdgcn_s_barrier();
        asm volatile("" ::: "memory");   // keep slot reads below the barrier
        // B fragments: read once per K-tile (8 x ds_read_b128)
        s16x8 bf[4][2];
        #pragma unroll
        for (int n = 0; n < 4; n++)
            #pragma unroll
            for (int kk = 0; kk < 2; kk++)
                bf[n][kk] = *(const s16x8*)&Bs[slot][(wn * 64 + n * 16 + lr) * 64 +
                                                     ((kk * 32 + lg * 8) ^ ((lr & 7) << 3))];
        #pragma unroll
        for (int q = 0; q < 4; q++) {
            s16x8 af[2][2];
            #pragma unroll
            for (int mm = 0; mm < 2; mm++)
                #pragma unroll
                for (int kk = 0; kk < 2; kk++)
                    af[mm][kk] = *(const s16x8*)&As[slot][(wm * 128 + (q * 2 + mm) * 16 + lr) * 64 +
                                                          ((kk * 32 + lg * 8) ^ ((lr & 7) << 3))];
            if (more && q < 3) {   // pairs #2..#4 for t+1
                GLL16(Ag + (size_t)(q + 1) * 64 * K + kn, &As[nslot][(q + 1) * 4096 + ldsoff]);
                GLL16(Bg + (size_t)(q + 1) * 64 * K + kn, &Bs[nslot][(q + 1) * 4096 + ldsoff]);
            }
            __builtin_amdgcn_s_barrier();
            __builtin_amdgcn_s_setprio(1);
            #pragma unroll
            for (int mm = 0; mm < 2; mm++)
                #pragma unroll
                for (int n = 0; n < 4; n++)
                    #pragma unroll
                    for (int kk = 0; kk < 2; kk++)
                        acc[q * 2 + mm][n] = __builtin_amdgcn_mfma_f32_16x16x32_bf16(
                            af[mm][kk], bf[n][kk], acc[q * 2 + mm][n], 0, 0, 0);
            __builtin_amdgcn_s_setprio(0);
            __builtin_amdgcn_s_barrier();
        }
    }
    int rbase = blockIdx.x * 256 + wm * 128;
    int cbase = blockIdx.y * 256 + wn * 64;
    #pragma unroll
    for (int am = 0; am < 8; am++)
        #pragma unroll
        for (int n = 0; n < 4; n++)
            #pragma unroll
            for (int r = 0; r < 4; r++) {
                int row = rbase + am * 16 + lg * 4 + r;
                int col = cbase + n * 16 + lr;
                float v = acc[am][n][r];
                if (OUTF32) ((float*)Cout)[(size_t)row * N + col] = v;
                else        ((unsigned short*)Cout)[(size_t)row * N + col] = f2bf(v);
            }
}

// ---------------- GEMM: 128x128 m97 structure (kept for gemm2, N=2048) ----------------
template<int OUTF32>
__global__ __launch_bounds__(256) void k_gemm_bt(const unsigned short* __restrict__ A,
                                                 const unsigned short* __restrict__ Bt,
                                                 void* __restrict__ Cout,
                                                 int M, int N, int K) {
    __shared__ unsigned short As[128 * 32];
    __shared__ unsigned short Bs[128 * 32];
    int tid = threadIdx.x;
    int lane = tid & 63;
    int wave = tid >> 6;
    int wm = wave >> 1, wn = wave & 1;
    int lr = lane & 15, lk = (lane >> 4) * 8;
    int srow = wave * 32 + (lane >> 2);
    int scol = (lane & 3) * 8;
    const unsigned short* Ag0 = A  + (size_t)(blockIdx.x * 128 + srow) * K + scol;
    const unsigned short* Ag1 = Ag0 + (size_t)16 * K;
    const unsigned short* Bg0 = Bt + (size_t)(blockIdx.y * 128 + srow) * K + scol;
    const unsigned short* Bg1 = Bg0 + (size_t)16 * K;
    unsigned short* Asw = &As[wave * 1024];
    unsigned short* Bsw = &Bs[wave * 1024];
    f32x4 acc[4][4] = {};
    for (int k0 = 0; k0 < K; k0 += 32) {
        __syncthreads();
        GLL16(Ag0 + k0, Asw);
        GLL16(Ag1 + k0, Asw + 512);
        GLL16(Bg0 + k0, Bsw);
        GLL16(Bg1 + k0, Bsw + 512);
        __syncthreads();
        s16x8 af[4], bfr[4];
        #pragma unroll
        for (int m = 0; m < 4; m++) af[m]  = *(const s16x8*)&As[(wm * 64 + m * 16 + lr) * 32 + lk];
        #pragma unroll
        for (int n = 0; n < 4; n++) bfr[n] = *(const s16x8*)&Bs[(wn * 64 + n * 16 + lr) * 32 + lk];
        #pragma unroll
        for (int m = 0; m < 4; m++)
            #pragma unroll
            for (int n = 0; n < 4; n++)
                acc[m][n] = __builtin_amdgcn_mfma_f32_16x16x32_bf16(af[m], bfr[n], acc[m][n], 0, 0, 0);
    }
    int rbase = blockIdx.x * 128 + wm * 64;
    int cbase = blockIdx.y * 128 + wn * 64;
    #pragma unroll
    for (int m = 0; m < 4; m++)
        #pragma unroll
        for (int n = 0; n < 4; n++)
            #pragma unroll
            for (int r = 0; r < 4; r++) {
                int row = rbase + m * 16 + (lane >> 4) * 4 + r;
                int col = cbase + n * 16 + lr;
                float v = acc[m][n][r];
                if (OUTF32) ((float*)Cout)[(size_t)row * N + col] = v;
                else        ((unsigned short*)Cout)[(size_t)row * N + col] = f2bf(v);
            }
}

// ---------------- fused RMSNorm + RoPE + head transpose ----------------
__global__ __launch_bounds__(256) void k_rms_rope(const unsigned short* __restrict__ qkv,
                                                  const float* __restrict__ qg,
                                                  const float* __restrict__ kg,
                                                  const float* __restrict__ cosc,
                                                  const float* __restrict__ sinc,
                                                  unsigned short* __restrict__ Qt,
                                                  unsigned short* __restrict__ Kt,
                                                  unsigned short* __restrict__ Vt) {
    int r = blockIdx.x;            // b*2048 + s
    int b = r >> 11;
    int s = r & 2047;
    int wave = threadIdx.x >> 6, lane = threadIdx.x & 63;
    const unsigned short* row = qkv + (size_t)r * 4096;
    float c  = cosc[s * 64 + lane];
    float sn = sinc[s * 64 + lane];
    for (int seg = wave; seg < 32; seg += 4) {
        int col0 = seg * 128;
        float e0 = bf2f(row[col0 + lane]);
        float e1 = bf2f(row[col0 + 64 + lane]);
        if (seg < 24) {
            float ss = e0 * e0 + e1 * e1;
            for (int m = 1; m < 64; m <<= 1) ss += __shfl_xor(ss, m, 64);
            float rn = rsqrtf(ss * (1.0f / 128.0f) + 1e-6f);
            const float* g = (seg < 16) ? qg : kg;
            float t0 = e0 * rn * g[lane];
            float t1 = e1 * rn * g[lane + 64];
            float o0 = t0 * c - t1 * sn;
            float o1 = t1 * c + t0 * sn;
            unsigned short* dst;
            if (seg < 16) dst = Qt + ((size_t)(b * 16 + seg) * 2048 + s) * 128;
            else          dst = Kt + ((size_t)(b * 8 + (seg - 16)) * 2048 + s) * 128;
            dst[lane]      = f2bf(o0);
            dst[lane + 64] = f2bf(o1);
        } else {
            unsigned short* dst = Vt + ((size_t)(b * 8 + (seg - 24)) * 2048 + s) * 128;
            dst[lane]      = row[col0 + lane];
            dst[lane + 64] = row[col0 + 64 + lane];
        }
    }
}

// ---------------- causal GQA flash attention (unchanged from R3) ----------------
__global__ __launch_bounds__(256) void k_attn(const unsigned short* __restrict__ Qt,
                                              const unsigned short* __restrict__ Kt,
                                              const unsigned short* __restrict__ Vtg,
                                              unsigned short* __restrict__ attn) {
    __shared__ unsigned short Ks[64][136];     // K tile [kv][d], padded
    __shared__ unsigned short Vs[128][72];     // V^T tile [d][kv], padded
    __shared__ unsigned short Ps[4][16][72];   // per-wave P tile [q][kv], padded
    int bid = blockIdx.x;                  // 0..511
    int lo = bid & 255;
    int qb, bh;
    if (bid < 256) { qb = lo & 15;        bh = lo >> 4; }
    else           { qb = 15 - (lo & 15); bh = 16 + (lo >> 4); }
    int b = bh >> 4, h = bh & 15;
    int kvh = h >> 1;
    int tid = threadIdx.x;
    int lane = tid & 63, wave = tid >> 6;
    int lr = lane & 15, lg = lane >> 4;
    int q0 = qb * 128;
    const unsigned short* Qb1 = Qt + ((size_t)bh * 2048 + q0 + wave * 16) * 128;
    const unsigned short* Qb2 = Qb1 + (size_t)64 * 128;
    const unsigned short* Kbase = Kt + (size_t)(b * 8 + kvh) * 2048 * 128;
    const unsigned short* Vtb   = Vtg + (size_t)(b * 8 + kvh) * 128 * 2048;   // [d][s]
    s16x8 aq1[4], aq2[4];
    #pragma unroll
    for (int f = 0; f < 4; f++) {
        aq1[f] = *(const s16x8*)(Qb1 + (size_t)lr * 128 + f * 32 + lg * 8);
        aq2[f] = *(const s16x8*)(Qb2 + (size_t)lr * 128 + f * 32 + lg * 8);
    }
    f32x4 o1[8] = {}, o2[8] = {};
    float m1 = -1e30f, l1 = 0.f, m2 = -1e30f, l2 = 0.f;
    int qg1 = q0 + wave * 16 + lr;
    int qg2 = qg1 + 64;
    const float scale = 0.08838834764831845f;  // 1/sqrt(128)
    int ntiles = 2 * qb + 2;
    int krow = tid >> 4, kcol = (tid & 15) * 8;
    int vrow = tid >> 3, vcol = (tid & 7) * 8;
    s16x8 kpre[4], vpre[4];
    #pragma unroll
    for (int p = 0; p < 4; p++) {
        kpre[p] = *(const s16x8*)(Kbase + (size_t)(krow + p * 16) * 128 + kcol);
        vpre[p] = *(const s16x8*)(Vtb + (size_t)(vrow + p * 32) * 2048 + vcol);
    }

    auto process = [&](const s16x8* aq, int qglob, float& m_q, float& l_q, f32x4* out, int k0) {
        f32x4 st[4] = {};
        __builtin_amdgcn_s_setprio(1);
        #pragma unroll
        for (int sub = 0; sub < 4; sub++)
            #pragma unroll
            for (int f = 0; f < 4; f++) {
                s16x8 bk = *(const s16x8*)&Ks[sub * 16 + lr][f * 32 + lg * 8];
                st[sub] = __builtin_amdgcn_mfma_f32_16x16x32_bf16(bk, aq[f], st[sub], 0, 0, 0);
            }
        __builtin_amdgcn_s_setprio(0);
        float pv[16];
        float mx = -1e30f;
        #pragma unroll
        for (int sub = 0; sub < 4; sub++)
            #pragma unroll
            for (int r = 0; r < 4; r++) {
                int kv = k0 + sub * 16 + lg * 4 + r;
                float v = (kv <= qglob) ? st[sub][r] * scale : -1e30f;
                pv[sub * 4 + r] = v;
                mx = fmaxf(mx, v);
            }
        mx = fmaxf(mx, __shfl_xor(mx, 16, 64));
        mx = fmaxf(mx, __shfl_xor(mx, 32, 64));
        float mnew = fmaxf(m_q, mx);
        float sf = __expf(m_q - mnew);
        m_q = mnew;
        float rs = 0.f;
        #pragma unroll
        for (int i = 0; i < 16; i++) { float e = __expf(pv[i] - mnew); pv[i] = e; rs += e; }
        rs += __shfl_xor(rs, 16, 64);
        rs += __shfl_xor(rs, 32, 64);
        l_q = l_q * sf + rs;
        #pragma unroll
        for (int sub = 0; sub < 4; sub++) {
            unsigned lop = (unsigned)f2bf(pv[sub * 4 + 0]) | ((unsigned)f2bf(pv[sub * 4 + 1]) << 16);
            unsigned hip_ = (unsigned)f2bf(pv[sub * 4 + 2]) | ((unsigned)f2bf(pv[sub * 4 + 3]) << 16);
            uint2 w; w.x = lop; w.y = hip_;
            *(uint2*)&Ps[wave][lr][sub * 16 + lg * 4] = w;
        }
        float sfr[4];
        #pragma unroll
        for (int r = 0; r < 4; r++) sfr[r] = __shfl(sf, lg * 4 + r, 64);
        #pragma unroll
        for (int blk = 0; blk < 8; blk++)
            #pragma unroll
            for (int r = 0; r < 4; r++) out[blk][r] *= sfr[r];
        __builtin_amdgcn_s_setprio(1);
        #pragma unroll
        for (int ks = 0; ks < 2; ks++) {
            s16x8 ap = *(const s16x8*)&Ps[wave][lr][ks * 32 + lg * 8];
            #pragma unroll
            for (int blk = 0; blk < 8; blk++) {
                s16x8 bv = *(const s16x8*)&Vs[blk * 16 + lr][ks * 32 + lg * 8];
                out[blk] = __builtin_amdgcn_mfma_f32_16x16x32_bf16(ap, bv, out[blk], 0, 0, 0);
            }
        }
        __builtin_amdgcn_s_setprio(0);
    };

    for (int t = 0; t < ntiles; t++) {
        int k0 = t * 64;
        __syncthreads();
        #pragma unroll
        for (int p = 0; p < 4; p++) *(s16x8*)&Ks[krow + p * 16][kcol] = kpre[p];
        #pragma unroll
        for (int p = 0; p < 4; p++) *(s16x8*)&Vs[vrow + p * 32][vcol] = vpre[p];
        __syncthreads();
        if (t + 1 < ntiles) {
            int kn = k0 + 64;
            #pragma unroll
            for (int p = 0; p < 4; p++) {
                kpre[p] = *(const s16x8*)(Kbase + (size_t)(kn + krow + p * 16) * 128 + kcol);
                vpre[p] = *(const s16x8*)(Vtb + (size_t)(vrow + p * 32) * 2048 + kn + vcol);
            }
        }
        process(aq2, qg2, m2, l2, o2, k0);
        if (k0 <= q0 + 63)
            process(aq1, qg1, m1, l1, o1, k0);
    }
    float li1 = 1.0f / l1, li2 = 1.0f / l2;
    float inv1[4], inv2[4];
    #pragma unroll
    for (int r = 0; r < 4; r++) {
        inv1[r] = __shfl(li1, lg * 4 + r, 64);
        inv2[r] = __shfl(li2, lg * 4 + r, 64);
    }
    #pragma unroll
    for (int blk = 0; blk < 8; blk++)
        #pragma unroll
        for (int r = 0; r < 4; r++) {
            int row1 = q0 + wave * 16 + lg * 4 + r;
            attn[((size_t)(b * 2048) + row1) * 2048 + h * 128 + blk * 16 + lr] =
                f2bf(o1[blk][r] * inv1[r]);
            attn[((size_t)(b * 2048) + row1 + 64) * 2048 + h * 128 + blk * 16 + lr] =
                f2bf(o2[blk][r] * inv2[r]);
        }
}

extern "C" void kernel_launch(void* const* d_in, const int* in_sizes, int n_in,
                              void* d_out, int out_size, void* d_ws, size_t ws_size,
                              hipStream_t stream) {
    const float* x    = (const float*)d_in[0];
    const float* wq   = (const float*)d_in[1];
    const float* wk   = (const float*)d_in[2];
    const float* wv   = (const float*)d_in[3];
    const float* wo   = (const float*)d_in[4];
    const float* qg   = (const float*)d_in[5];
    const float* kg   = (const float*)d_in[6];
    const float* cosc = (const float*)d_in[7];
    const float* sinc = (const float*)d_in[8];

    char* ws = (char*)d_ws;
    unsigned short* xb   = (unsigned short*)(ws);                 // 16 MiB  x bf16 (4096x2048)
    unsigned short* w1t  = (unsigned short*)(ws + 16777216);      // 16 MiB  [wq|wk|wv]^T (4096x2048)
    unsigned short* w2t  = (unsigned short*)(ws + 33554432);      //  8 MiB  wo^T (2048x2048)
    unsigned short* qkv  = (unsigned short*)(ws + 41943040);      // 32 MiB  (4096x4096); dead after k_rms_rope
    unsigned short* Qt   = (unsigned short*)(ws + 75497472);      // 16 MiB  (2,16,2048,128)
    unsigned short* Kt   = (unsigned short*)(ws + 92274688);      //  8 MiB  (2,8,2048,128)
    unsigned short* Vt   = (unsigned short*)(ws + 100663296);     //  8 MiB  (2,8,2048,128)
    unsigned short* attn = (unsigned short*)(ws + 109051904);     // 16 MiB  (4096x2048)
    unsigned short* Vtg  = qkv;                                   //  8 MiB  (2,8,128,2048) reuses qkv

    k_convert_x<<<4096, 256, 0, stream>>>(x, xb, 8388608);
    k_transpose_w<<<dim3(64, 64), 256, 0, stream>>>(wq, w1t, 2048, 2048, 0, 2048);
    k_transpose_w<<<dim3(64, 32), 256, 0, stream>>>(wk, w1t, 2048, 1024, 2048, 2048);
    k_transpose_w<<<dim3(64, 32), 256, 0, stream>>>(wv, w1t, 2048, 1024, 3072, 2048);
    k_transpose_w<<<dim3(64, 64), 256, 0, stream>>>(wo, w2t, 2048, 2048, 0, 2048);
    k_gemm256<0><<<dim3(16, 16), 512, 0, stream>>>(xb, w1t, qkv, 4096, 4096, 2048);
    k_rms_rope<<<4096, 256, 0, stream>>>(qkv, qg, kg, cosc, sinc, Qt, Kt, Vt);
    k_transpose_v<<<dim3(64, 4, 16), 256, 0, stream>>>(Vt, Vtg);
    k_attn<<<512, 256, 0, stream>>>(Qt, Kt, Vtg, attn);
    k_gemm_bt<1><<<dim3(32, 16), 256, 0, stream>>>(attn, w2t, d_out, 4096, 2048, 2048);
}

// Round 6
// 252.413 us; speedup vs baseline: 2.0568x; 1.2059x over previous
//
#include <hip/hip_runtime.h>
#include <hip/hip_bf16.h>

// Problem constants: B=2, S=2048, DIM=2048, H=16, KVH=8, D=128

typedef __attribute__((ext_vector_type(8))) short s16x8;   // 8 bf16 in 4 VGPRs
typedef __attribute__((ext_vector_type(4))) float f32x4;

typedef const __attribute__((address_space(1))) void* gas_t;
typedef __attribute__((address_space(3))) void* las_t;
#define GLL16(g, l) __builtin_amdgcn_global_load_lds((gas_t)(const void*)(g), (las_t)(void*)(l), 16, 0, 0)

static __device__ __forceinline__ unsigned short f2bf(float f) {
    union { float f; unsigned u; } v; v.f = f;
    unsigned r = v.u + 0x7FFF + ((v.u >> 16) & 1);   // RNE
    return (unsigned short)(r >> 16);
}
static __device__ __forceinline__ float bf2f(unsigned short h) {
    union { unsigned u; float f; } v; v.u = ((unsigned)h) << 16;
    return v.f;
}

// ---------------- f32 -> bf16 elementwise convert (x) ----------------
__global__ __launch_bounds__(256) void k_convert_x(const float* __restrict__ x,
                                                   unsigned short* __restrict__ xb, int n) {
    int i = (blockIdx.x * 256 + threadIdx.x) * 8;
    if (i >= n) return;
    float4 a = *(const float4*)(x + i);
    float4 b = *(const float4*)(x + i + 4);
    s16x8 o;
    o[0] = (short)f2bf(a.x); o[1] = (short)f2bf(a.y); o[2] = (short)f2bf(a.z); o[3] = (short)f2bf(a.w);
    o[4] = (short)f2bf(b.x); o[5] = (short)f2bf(b.y); o[6] = (short)f2bf(b.z); o[7] = (short)f2bf(b.w);
    *(s16x8*)(xb + i) = o;
}

// ---------------- weight transpose f32 (K x N) -> bf16 (N x K) ----------------
__global__ __launch_bounds__(256) void k_transpose_w(const float* __restrict__ src,
                                                     unsigned short* __restrict__ dst,
                                                     int K, int N, int nbase, int dstld) {
    __shared__ float t[32][33];
    int k0 = blockIdx.x * 32, n0 = blockIdx.y * 32;
    int tx = threadIdx.x & 31, ty0 = threadIdx.x >> 5;
    for (int p = 0; p < 4; p++) {
        int ty = ty0 + p * 8;
        t[ty][tx] = src[(size_t)(k0 + ty) * N + n0 + tx];
    }
    __syncthreads();
    for (int p = 0; p < 4; p++) {
        int ty = ty0 + p * 8;
        dst[(size_t)(nbase + n0 + ty) * dstld + k0 + tx] = f2bf(t[tx][ty]);
    }
}

// ---------------- bf16 transpose: V (2048 x 128) -> Vt (128 x 2048), per (b,kvh) ----------------
__global__ __launch_bounds__(256) void k_transpose_v(const unsigned short* __restrict__ V,
                                                     unsigned short* __restrict__ Vt) {
    __shared__ unsigned short t[32][33];
    int s0 = blockIdx.x * 32, d0 = blockIdx.y * 32;
    size_t base = (size_t)blockIdx.z * 2048 * 128;
    int tx = threadIdx.x & 31, ty0 = threadIdx.x >> 5;
    for (int p = 0; p < 4; p++) {
        int ty = ty0 + p * 8;
        t[ty][tx] = V[base + (size_t)(s0 + ty) * 128 + d0 + tx];
    }
    __syncthreads();
    for (int p = 0; p < 4; p++) {
        int ty = ty0 + p * 8;
        Vt[base + (size_t)(d0 + ty) * 2048 + s0 + tx] = t[tx][ty];
    }
}

// ---------------- 8-phase 256x256 GEMM: C = A(MxK) * Bt(NxK)^T ----------------
template<int OUTF32>
__global__ __launch_bounds__(512, 2) void k_gemm256(const unsigned short* __restrict__ A,
                                                    const unsigned short* __restrict__ Bt,
                                                    void* __restrict__ Cout,
                                                    int M, int N, int K) {
    __shared__ unsigned short As[2][256 * 64];
    __shared__ unsigned short Bs[2][256 * 64];
    int tid = threadIdx.x, lane = tid & 63, wave = tid >> 6;
    int wm = wave >> 2, wn = wave & 3;
    int lr = lane & 15, lg = lane >> 4;
    int srow = wave * 8 + (lane >> 3);
    int scol = (((lane & 7) ^ (lane >> 3)) * 8);
    const unsigned short* Ag = A  + (size_t)(blockIdx.x * 256 + srow) * K + scol;
    const unsigned short* Bg = Bt + (size_t)(blockIdx.y * 256 + srow) * K + scol;
    int ldsoff = wave * 512;

    f32x4 acc[8][4] = {};
    int NK = K / 64;
    #pragma unroll
    for (int p = 0; p < 4; p++) {
        GLL16(Ag + (size_t)p * 64 * K, &As[0][p * 4096 + ldsoff]);
        GLL16(Bg + (size_t)p * 64 * K, &Bs[0][p * 4096 + ldsoff]);
    }
    for (int t = 0; t < NK; ++t) {
        int slot = t & 1, nslot = slot ^ 1;
        size_t kn = (size_t)(t + 1) * 64;
        bool more = (t + 1) < NK;
        if (more) {
            GLL16(Ag + kn, &As[nslot][ldsoff]);
            GLL16(Bg + kn, &Bs[nslot][ldsoff]);
            asm volatile("s_waitcnt vmcnt(2)" ::: "memory");
        } else {
            asm volatile("s_waitcnt vmcnt(0)" ::: "memory");
        }
        __builtin_amdgcn_s_barrier();
        asm volatile("" ::: "memory");
        s16x8 bf[4][2];
        #pragma unroll
        for (int n = 0; n < 4; n++)
            #pragma unroll
            for (int kk = 0; kk < 2; kk++)
                bf[n][kk] = *(const s16x8*)&Bs[slot][(wn * 64 + n * 16 + lr) * 64 +
                                                     ((kk * 32 + lg * 8) ^ ((lr & 7) << 3))];
        #pragma unroll
        for (int q = 0; q < 4; q++) {
            s16x8 af[2][2];
            #pragma unroll
            for (int mm = 0; mm < 2; mm++)
                #pragma unroll
                for (int kk = 0; kk < 2; kk++)
                    af[mm][kk] = *(const s16x8*)&As[slot][(wm * 128 + (q * 2 + mm) * 16 + lr) * 64 +
                                                          ((kk * 32 + lg * 8) ^ ((lr & 7) << 3))];
            if (more && q < 3) {
                GLL16(Ag + (size_t)(q + 1) * 64 * K + kn, &As[nslot][(q + 1) * 4096 + ldsoff]);
                GLL16(Bg + (size_t)(q + 1) * 64 * K + kn, &Bs[nslot][(q + 1) * 4096 + ldsoff]);
            }
            __builtin_amdgcn_s_barrier();
            __builtin_amdgcn_s_setprio(1);
            #pragma unroll
            for (int mm = 0; mm < 2; mm++)
                #pragma unroll
                for (int n = 0; n < 4; n++)
                    #pragma unroll
                    for (int kk = 0; kk < 2; kk++)
                        acc[q * 2 + mm][n] = __builtin_amdgcn_mfma_f32_16x16x32_bf16(
                            af[mm][kk], bf[n][kk], acc[q * 2 + mm][n], 0, 0, 0);
            __builtin_amdgcn_s_setprio(0);
            __builtin_amdgcn_s_barrier();
        }
    }
    int rbase = blockIdx.x * 256 + wm * 128;
    int cbase = blockIdx.y * 256 + wn * 64;
    #pragma unroll
    for (int am = 0; am < 8; am++)
        #pragma unroll
        for (int n = 0; n < 4; n++)
            #pragma unroll
            for (int r = 0; r < 4; r++) {
                int row = rbase + am * 16 + lg * 4 + r;
                int col = cbase + n * 16 + lr;
                float v = acc[am][n][r];
                if (OUTF32) ((float*)Cout)[(size_t)row * N + col] = v;
                else        ((unsigned short*)Cout)[(size_t)row * N + col] = f2bf(v);
            }
}

// ---------------- GEMM: 128x128 m97 structure (kept for gemm2, N=2048) ----------------
template<int OUTF32>
__global__ __launch_bounds__(256) void k_gemm_bt(const unsigned short* __restrict__ A,
                                                 const unsigned short* __restrict__ Bt,
                                                 void* __restrict__ Cout,
                                                 int M, int N, int K) {
    __shared__ unsigned short As[128 * 32];
    __shared__ unsigned short Bs[128 * 32];
    int tid = threadIdx.x;
    int lane = tid & 63;
    int wave = tid >> 6;
    int wm = wave >> 1, wn = wave & 1;
    int lr = lane & 15, lk = (lane >> 4) * 8;
    int srow = wave * 32 + (lane >> 2);
    int scol = (lane & 3) * 8;
    const unsigned short* Ag0 = A  + (size_t)(blockIdx.x * 128 + srow) * K + scol;
    const unsigned short* Ag1 = Ag0 + (size_t)16 * K;
    const unsigned short* Bg0 = Bt + (size_t)(blockIdx.y * 128 + srow) * K + scol;
    const unsigned short* Bg1 = Bg0 + (size_t)16 * K;
    unsigned short* Asw = &As[wave * 1024];
    unsigned short* Bsw = &Bs[wave * 1024];
    f32x4 acc[4][4] = {};
    for (int k0 = 0; k0 < K; k0 += 32) {
        __syncthreads();
        GLL16(Ag0 + k0, Asw);
        GLL16(Ag1 + k0, Asw + 512);
        GLL16(Bg0 + k0, Bsw);
        GLL16(Bg1 + k0, Bsw + 512);
        __syncthreads();
        s16x8 af[4], bfr[4];
        #pragma unroll
        for (int m = 0; m < 4; m++) af[m]  = *(const s16x8*)&As[(wm * 64 + m * 16 + lr) * 32 + lk];
        #pragma unroll
        for (int n = 0; n < 4; n++) bfr[n] = *(const s16x8*)&Bs[(wn * 64 + n * 16 + lr) * 32 + lk];
        #pragma unroll
        for (int m = 0; m < 4; m++)
            #pragma unroll
            for (int n = 0; n < 4; n++)
                acc[m][n] = __builtin_amdgcn_mfma_f32_16x16x32_bf16(af[m], bfr[n], acc[m][n], 0, 0, 0);
    }
    int rbase = blockIdx.x * 128 + wm * 64;
    int cbase = blockIdx.y * 128 + wn * 64;
    #pragma unroll
    for (int m = 0; m < 4; m++)
        #pragma unroll
        for (int n = 0; n < 4; n++)
            #pragma unroll
            for (int r = 0; r < 4; r++) {
                int row = rbase + m * 16 + (lane >> 4) * 4 + r;
                int col = cbase + n * 16 + lr;
                float v = acc[m][n][r];
                if (OUTF32) ((float*)Cout)[(size_t)row * N + col] = v;
                else        ((unsigned short*)Cout)[(size_t)row * N + col] = f2bf(v);
            }
}

// ---------------- fused RMSNorm + RoPE + head transpose ----------------
__global__ __launch_bounds__(256) void k_rms_rope(const unsigned short* __restrict__ qkv,
                                                  const float* __restrict__ qg,
                                                  const float* __restrict__ kg,
                                                  const float* __restrict__ cosc,
                                                  const float* __restrict__ sinc,
                                                  unsigned short* __restrict__ Qt,
                                                  unsigned short* __restrict__ Kt,
                                                  unsigned short* __restrict__ Vt) {
    int r = blockIdx.x;            // b*2048 + s
    int b = r >> 11;
    int s = r & 2047;
    int wave = threadIdx.x >> 6, lane = threadIdx.x & 63;
    const unsigned short* row = qkv + (size_t)r * 4096;
    float c  = cosc[s * 64 + lane];
    float sn = sinc[s * 64 + lane];
    for (int seg = wave; seg < 32; seg += 4) {
        int col0 = seg * 128;
        float e0 = bf2f(row[col0 + lane]);
        float e1 = bf2f(row[col0 + 64 + lane]);
        if (seg < 24) {
            float ss = e0 * e0 + e1 * e1;
            for (int m = 1; m < 64; m <<= 1) ss += __shfl_xor(ss, m, 64);
            float rn = rsqrtf(ss * (1.0f / 128.0f) + 1e-6f);
            const float* g = (seg < 16) ? qg : kg;
            float t0 = e0 * rn * g[lane];
            float t1 = e1 * rn * g[lane + 64];
            float o0 = t0 * c - t1 * sn;
            float o1 = t1 * c + t0 * sn;
            unsigned short* dst;
            if (seg < 16) dst = Qt + ((size_t)(b * 16 + seg) * 2048 + s) * 128;
            else          dst = Kt + ((size_t)(b * 8 + (seg - 16)) * 2048 + s) * 128;
            dst[lane]      = f2bf(o0);
            dst[lane + 64] = f2bf(o1);
        } else {
            unsigned short* dst = Vt + ((size_t)(b * 8 + (seg - 24)) * 2048 + s) * 128;
            dst[lane]      = row[col0 + lane];
            dst[lane + 64] = row[col0 + 64 + lane];
        }
    }
}

// ---------------- causal GQA flash attention ----------------
// 8 waves/block, QBLK=128 (one 16-row fragment per wave), KVBLK=64
// Swapped QK^T -> lane-local softmax (st reused in place); register prefetch;
// duration-balanced block swizzle; 4 waves/SIMD target.
__global__ __launch_bounds__(512, 4) void k_attn(const unsigned short* __restrict__ Qt,
                                                 const unsigned short* __restrict__ Kt,
                                                 const unsigned short* __restrict__ Vtg,
                                                 unsigned short* __restrict__ attn) {
    __shared__ unsigned short Ks[64][136];     // K tile [kv][d], padded
    __shared__ unsigned short Vs[128][72];     // V^T tile [d][kv], padded
    __shared__ unsigned short Ps[8][16][72];   // per-wave P tile [q][kv], padded
    int bid = blockIdx.x;                  // 0..511
    int lo = bid & 255;
    int qb, bh;
    if (bid < 256) { qb = lo & 15;        bh = lo >> 4; }
    else           { qb = 15 - (lo & 15); bh = 16 + (lo >> 4); }
    int b = bh >> 4, h = bh & 15;
    int kvh = h >> 1;
    int tid = threadIdx.x;
    int lane = tid & 63, wave = tid >> 6;
    int lr = lane & 15, lg = lane >> 4;
    int q0 = qb * 128;
    const unsigned short* Qb1 = Qt + ((size_t)bh * 2048 + q0 + wave * 16) * 128;
    const unsigned short* Kbase = Kt + (size_t)(b * 8 + kvh) * 2048 * 128;
    const unsigned short* Vtb   = Vtg + (size_t)(b * 8 + kvh) * 128 * 2048;   // [d][s]
    s16x8 aq[4];
    #pragma unroll
    for (int f = 0; f < 4; f++)
        aq[f] = *(const s16x8*)(Qb1 + (size_t)lr * 128 + f * 32 + lg * 8);
    f32x4 out[8] = {};
    float m_q = -1e30f, l_q = 0.f;
    int qglob = q0 + wave * 16 + lr;
    int qhi   = q0 + wave * 16 + 15;       // wave-uniform activity bound
    const float scale = 0.08838834764831845f;  // 1/sqrt(128)
    int ntiles = 2 * qb + 2;
    // staging coords (512 threads)
    int krow = tid >> 4, kcol = (tid & 15) * 8;   // K: 32 rows x 128 cols per pass, 2 passes
    int vrow = tid >> 3, vcol = (tid & 7) * 8;    // V^T: 64 rows x 64 cols per pass, 2 passes
    s16x8 kpre[2], vpre[2];
    #pragma unroll
    for (int p = 0; p < 2; p++) {
        kpre[p] = *(const s16x8*)(Kbase + (size_t)(krow + p * 32) * 128 + kcol);
        vpre[p] = *(const s16x8*)(Vtb + (size_t)(vrow + p * 64) * 2048 + vcol);
    }

    for (int t = 0; t < ntiles; t++) {
        int k0 = t * 64;
        __syncthreads();   // previous tile's LDS reads complete
        #pragma unroll
        for (int p = 0; p < 2; p++) {
            *(s16x8*)&Ks[krow + p * 32][kcol] = kpre[p];
            *(s16x8*)&Vs[vrow + p * 64][vcol] = vpre[p];
        }
        __syncthreads();
        if (t + 1 < ntiles) {
            int kn = k0 + 64;
            #pragma unroll
            for (int p = 0; p < 2; p++) {
                kpre[p] = *(const s16x8*)(Kbase + (size_t)(kn + krow + p * 32) * 128 + kcol);
                vpre[p] = *(const s16x8*)(Vtb + (size_t)(vrow + p * 64) * 2048 + kn + vcol);
            }
        }
        if (k0 <= qhi) {
            // swapped QK^T: S^T[kv][q], A-frag = K rows, B-frag = Q
            f32x4 st[4] = {};
            __builtin_amdgcn_s_setprio(1);
            #pragma unroll
            for (int sub = 0; sub < 4; sub++)
                #pragma unroll
                for (int f = 0; f < 4; f++) {
                    s16x8 bk = *(const s16x8*)&Ks[sub * 16 + lr][f * 32 + lg * 8];
                    st[sub] = __builtin_amdgcn_mfma_f32_16x16x32_bf16(bk, aq[f], st[sub], 0, 0, 0);
                }
            __builtin_amdgcn_s_setprio(0);
            // softmax in place: lane holds 16 values of row q=qglob
            float mx = -1e30f;
            #pragma unroll
            for (int sub = 0; sub < 4; sub++)
                #pragma unroll
                for (int r = 0; r < 4; r++) {
                    int kv = k0 + sub * 16 + lg * 4 + r;
                    float v = (kv <= qglob) ? st[sub][r] * scale : -1e30f;
                    st[sub][r] = v;
                    mx = fmaxf(mx, v);
                }
            mx = fmaxf(mx, __shfl_xor(mx, 16, 64));
            mx = fmaxf(mx, __shfl_xor(mx, 32, 64));
            float mnew = fmaxf(m_q, mx);
            float sf = __expf(m_q - mnew);
            m_q = mnew;
            float rs = 0.f;
            #pragma unroll
            for (int sub = 0; sub < 4; sub++)
                #pragma unroll
                for (int r = 0; r < 4; r++) {
                    float e = __expf(st[sub][r] - mnew);
                    st[sub][r] = e;
                    rs += e;
                }
            rs += __shfl_xor(rs, 16, 64);
            rs += __shfl_xor(rs, 32, 64);
            l_q = l_q * sf + rs;
            // pack P -> Ps[q][kv], vectorized b64 writes
            #pragma unroll
            for (int sub = 0; sub < 4; sub++) {
                unsigned lop  = (unsigned)f2bf(st[sub][0]) | ((unsigned)f2bf(st[sub][1]) << 16);
                unsigned hip_ = (unsigned)f2bf(st[sub][2]) | ((unsigned)f2bf(st[sub][3]) << 16);
                uint2 w; w.x = lop; w.y = hip_;
                *(uint2*)&Ps[wave][lr][sub * 16 + lg * 4] = w;
            }
            // rescale accumulator (per out row q = lg*4 + r)
            float sfr[4];
            #pragma unroll
            for (int r = 0; r < 4; r++) sfr[r] = __shfl(sf, lg * 4 + r, 64);
            #pragma unroll
            for (int blk = 0; blk < 8; blk++)
                #pragma unroll
                for (int r = 0; r < 4; r++) out[blk][r] *= sfr[r];
            // PV: P (16x64) x V^T tile
            __builtin_amdgcn_s_setprio(1);
            #pragma unroll
            for (int ks = 0; ks < 2; ks++) {
                s16x8 ap = *(const s16x8*)&Ps[wave][lr][ks * 32 + lg * 8];
                #pragma unroll
                for (int blk = 0; blk < 8; blk++) {
                    s16x8 bv = *(const s16x8*)&Vs[blk * 16 + lr][ks * 32 + lg * 8];
                    out[blk] = __builtin_amdgcn_mfma_f32_16x16x32_bf16(ap, bv, out[blk], 0, 0, 0);
                }
            }
            __builtin_amdgcn_s_setprio(0);
        }
    }
    float linv = 1.0f / l_q;
    float inv[4];
    #pragma unroll
    for (int r = 0; r < 4; r++) inv[r] = __shfl(linv, lg * 4 + r, 64);
    #pragma unroll
    for (int blk = 0; blk < 8; blk++)
        #pragma unroll
        for (int r = 0; r < 4; r++) {
            int row = q0 + wave * 16 + lg * 4 + r;
            attn[((size_t)(b * 2048) + row) * 2048 + h * 128 + blk * 16 + lr] =
                f2bf(out[blk][r] * inv[r]);
        }
}

extern "C" void kernel_launch(void* const* d_in, const int* in_sizes, int n_in,
                              void* d_out, int out_size, void* d_ws, size_t ws_size,
                              hipStream_t stream) {
    const float* x    = (const float*)d_in[0];
    const float* wq   = (const float*)d_in[1];
    const float* wk   = (const float*)d_in[2];
    const float* wv   = (const float*)d_in[3];
    const float* wo   = (const float*)d_in[4];
    const float* qg   = (const float*)d_in[5];
    const float* kg   = (const float*)d_in[6];
    const float* cosc = (const float*)d_in[7];
    const float* sinc = (const float*)d_in[8];

    char* ws = (char*)d_ws;
    unsigned short* xb   = (unsigned short*)(ws);                 // 16 MiB  x bf16 (4096x2048)
    unsigned short* w1t  = (unsigned short*)(ws + 16777216);      // 16 MiB  [wq|wk|wv]^T (4096x2048)
    unsigned short* w2t  = (unsigned short*)(ws + 33554432);      //  8 MiB  wo^T (2048x2048)
    unsigned short* qkv  = (unsigned short*)(ws + 41943040);      // 32 MiB  (4096x4096); dead after k_rms_rope
    unsigned short* Qt   = (unsigned short*)(ws + 75497472);      // 16 MiB  (2,16,2048,128)
    unsigned short* Kt   = (unsigned short*)(ws + 92274688);      //  8 MiB  (2,8,2048,128)
    unsigned short* Vt   = (unsigned short*)(ws + 100663296);     //  8 MiB  (2,8,2048,128)
    unsigned short* attn = (unsigned short*)(ws + 109051904);     // 16 MiB  (4096x2048)
    unsigned short* Vtg  = qkv;                                   //  8 MiB  (2,8,128,2048) reuses qkv

    k_convert_x<<<4096, 256, 0, stream>>>(x, xb, 8388608);
    k_transpose_w<<<dim3(64, 64), 256, 0, stream>>>(wq, w1t, 2048, 2048, 0, 2048);
    k_transpose_w<<<dim3(64, 32), 256, 0, stream>>>(wk, w1t, 2048, 1024, 2048, 2048);
    k_transpose_w<<<dim3(64, 32), 256, 0, stream>>>(wv, w1t, 2048, 1024, 3072, 2048);
    k_transpose_w<<<dim3(64, 64), 256, 0, stream>>>(wo, w2t, 2048, 2048, 0, 2048);
    k_gemm256<0><<<dim3(16, 16), 512, 0, stream>>>(xb, w1t, qkv, 4096, 4096, 2048);
    k_rms_rope<<<4096, 256, 0, stream>>>(qkv, qg, kg, cosc, sinc, Qt, Kt, Vt);
    k_transpose_v<<<dim3(64, 4, 16), 256, 0, stream>>>(Vt, Vtg);
    k_attn<<<512, 512, 0, stream>>>(Qt, Kt, Vtg, attn);
    k_gemm_bt<1><<<dim3(32, 16), 256, 0, stream>>>(attn, w2t, d_out, 4096, 2048, 2048);
}